// Round 4
// baseline (1467.242 us; speedup 1.0000x reference)
//
#include <hip/hip_runtime.h>
#include <math.h>

// Problem constants
#define NB   64
#define NN   400
#define DD   256
#define NHH  4
#define HDD  64
#define MR   25600            // NB*NN
#define KP448 448             // 400 padded to multiple of 64

typedef __attribute__((ext_vector_type(8))) short bf16x8;
typedef __attribute__((ext_vector_type(4))) float f32x4;

__device__ __forceinline__ short f2bf(float x) {
    union { float f; unsigned u; } v; v.f = x;
    return (short)((v.u + 0x7FFFu + ((v.u >> 16) & 1u)) >> 16);
}
__device__ __forceinline__ float bf2f(short s) {
    union { unsigned u; float f; } v; v.u = ((unsigned)(unsigned short)s) << 16;
    return v.f;
}
// async global->LDS, 16 B/lane; LDS dest = wave-uniform base + lane*16
__device__ __forceinline__ void gl_lds16(const void* g, void* l) {
    __builtin_amdgcn_global_load_lds(
        (const __attribute__((address_space(1))) unsigned*)g,
        (__attribute__((address_space(3))) unsigned*)l, 16, 0, 0);
}

// ---------------------------------------------------------------------------
// P8 layout: element (row, k) of a [rows x K] tensor lives at
//   ((k>>3)*rows + row)*8 + (k&7)      (bf16 shorts)
// This IS the 16x16x32 MFMA fragment layout, so global->LDS staging is
// contiguous 1 KiB bursts per wave instruction.
// ---------------------------------------------------------------------------

// bf16 GEMM, 128x128 tile, BK=64, both operands P8.
// C(m,n) = act(sum_k A(m,k)*B(n,k) + bias[n]); C written in P8 (plane=n>>3).
// K % 64 == 0. Staging may overrun rows (garbage rows -> unstored C rows).
__global__ __launch_bounds__(256) void gemm_p8(
    const short* __restrict__ A, int arows, long long sA,
    const short* __restrict__ B, int brows, long long sB,
    const float* __restrict__ bias,
    short* __restrict__ C, int crows, int crz, long long sCe,
    int M, int N, int Npad, int K, int relu)
{
    __shared__ short Al[8 * 128 * 8];   // [plane][128 rows][8]
    __shared__ short Bl[8 * 128 * 8];
    const int tid = threadIdx.x;
    const int z = blockIdx.z;
    const int m0 = blockIdx.y * 128, n0 = blockIdx.x * 128;
    const short* Ab = A + (size_t)z * sA;
    const short* Bb = B + (size_t)z * sB;

    const int w = tid >> 6, lane = tid & 63;
    const int quad = lane >> 4, l15 = lane & 15;
    const int wm = w & 1, wn = w >> 1;

    f32x4 acc[4][4] = {};

    const int KT = K >> 6;
    for (int kt = 0; kt < KT; ++kt) {
        const int gp0 = kt << 3;
#pragma unroll
        for (int pp = 0; pp < 2; ++pp) {
            const int p = w + pp * 4;
            gl_lds16(Ab + ((size_t)(gp0 + p) * arows + m0 + lane) * 8,       &Al[(p * 128) * 8]);
            gl_lds16(Ab + ((size_t)(gp0 + p) * arows + m0 + 64 + lane) * 8,  &Al[(p * 128 + 64) * 8]);
            gl_lds16(Bb + ((size_t)(gp0 + p) * brows + n0 + lane) * 8,       &Bl[(p * 128) * 8]);
            gl_lds16(Bb + ((size_t)(gp0 + p) * brows + n0 + 64 + lane) * 8,  &Bl[(p * 128 + 64) * 8]);
        }
        __syncthreads();
#pragma unroll
        for (int kb = 0; kb < 2; ++kb) {
            bf16x8 af[4], bfr[4];
#pragma unroll
            for (int mi = 0; mi < 4; ++mi)
                af[mi] = *reinterpret_cast<const bf16x8*>(
                    &Al[((kb * 4 + quad) * 128 + wm * 64 + mi * 16 + l15) * 8]);
#pragma unroll
            for (int ni = 0; ni < 4; ++ni)
                bfr[ni] = *reinterpret_cast<const bf16x8*>(
                    &Bl[((kb * 4 + quad) * 128 + wn * 64 + ni * 16 + l15) * 8]);
#pragma unroll
            for (int mi = 0; mi < 4; ++mi)
#pragma unroll
                for (int ni = 0; ni < 4; ++ni)
                    acc[mi][ni] = __builtin_amdgcn_mfma_f32_16x16x32_bf16(af[mi], bfr[ni], acc[mi][ni], 0, 0, 0);
        }
        __syncthreads();
    }

    short* Cbz = C + (size_t)z * sCe;
    const long long zr = (long long)z * crz;
#pragma unroll
    for (int mi = 0; mi < 4; ++mi) {
#pragma unroll
        for (int r = 0; r < 4; ++r) {
            int row = m0 + wm * 64 + mi * 16 + quad * 4 + r;
            if (row >= M) continue;
#pragma unroll
            for (int ni = 0; ni < 4; ++ni) {
                int col = n0 + wn * 64 + ni * 16 + l15;
                if (col >= Npad) continue;
                float v = 0.0f;
                if (col < N) {
                    v = acc[mi][ni][r];
                    if (bias) v += bias[col];
                    if (relu) v = fmaxf(v, 0.0f);
                }
                Cbz[((size_t)(col >> 3) * crows + zr + row) * 8 + (col & 7)] = f2bf(v);
            }
        }
    }
}

// ---------------------------------------------------------------------------
// Attention over P8 QKV buffer (96 planes x MR rows x 8).
// Q: planes 8h..8h+7 ; K: 32+8h.. ; V: 64+8h..  Out -> P8 (32 planes x MR).
// Block = (64-q-row tile, head, batch).
// ---------------------------------------------------------------------------
__global__ __launch_bounds__(256) void attn_p8(
    const short* __restrict__ qkv, short* __restrict__ Out)
{
    __shared__ short KP[8 * 448 * 8];   // K planes [8][448][8]; later P [52][64][8]
    __shared__ short QV[8 * 64 * 8];    // Q [8][64][8]; later V chunks [8][64][8]
    const int qt = blockIdx.x, h = blockIdx.y, b = blockIdx.z;
    const int tid = threadIdx.x;
    const int w = tid >> 6, lane = tid & 63;
    const int quad = lane >> 4, l15 = lane & 15;
    const size_t rowb = (size_t)b * NN;

    // stage Q: plane j, rows qt*64 .. +63 (coalesced 1 KiB)
    for (int j = w; j < 8; j += 4)
        gl_lds16(qkv + (((size_t)(8 * h + j)) * MR + rowb + qt * 64 + lane) * 8, &QV[(j * 64) * 8]);
    // stage K: 8 planes x 448 rows (rows>=400 garbage, never used)
    for (int t = w; t < 56; t += 4) {
        int j = t / 7, c = t - j * 7;
        gl_lds16(qkv + (((size_t)(32 + 8 * h + j)) * MR + rowb + c * 64 + lane) * 8,
                 &KP[(j * 448 + c * 64) * 8]);
    }
    __syncthreads();

    // phase 1: S = Q K^T (wave's 16 q rows x 400 keys)
    bf16x8 aq0 = *reinterpret_cast<const bf16x8*>(&QV[(quad * 64 + w * 16 + l15) * 8]);
    bf16x8 aq1 = *reinterpret_cast<const bf16x8*>(&QV[((4 + quad) * 64 + w * 16 + l15) * 8]);
    f32x4 sacc[25];
#pragma unroll
    for (int nt = 0; nt < 25; ++nt) { sacc[nt][0] = 0; sacc[nt][1] = 0; sacc[nt][2] = 0; sacc[nt][3] = 0; }
#pragma unroll
    for (int nt = 0; nt < 25; ++nt) {
        bf16x8 b0 = *reinterpret_cast<const bf16x8*>(&KP[(quad * 448 + nt * 16 + l15) * 8]);
        bf16x8 b1 = *reinterpret_cast<const bf16x8*>(&KP[((4 + quad) * 448 + nt * 16 + l15) * 8]);
        sacc[nt] = __builtin_amdgcn_mfma_f32_16x16x32_bf16(aq0, b0, sacc[nt], 0, 0, 0);
        sacc[nt] = __builtin_amdgcn_mfma_f32_16x16x32_bf16(aq1, b1, sacc[nt], 0, 0, 0);
    }

    // softmax (rows quad*4+r, col nt*16+l15)
    float mx[4] = {-3e38f, -3e38f, -3e38f, -3e38f}, sm[4] = {0, 0, 0, 0};
#pragma unroll
    for (int nt = 0; nt < 25; ++nt)
#pragma unroll
        for (int r = 0; r < 4; ++r) mx[r] = fmaxf(mx[r], sacc[nt][r]);
#pragma unroll
    for (int r = 0; r < 4; ++r) {
        mx[r] = fmaxf(mx[r], __shfl_xor(mx[r], 1));
        mx[r] = fmaxf(mx[r], __shfl_xor(mx[r], 2));
        mx[r] = fmaxf(mx[r], __shfl_xor(mx[r], 4));
        mx[r] = fmaxf(mx[r], __shfl_xor(mx[r], 8));
    }
#pragma unroll
    for (int nt = 0; nt < 25; ++nt)
#pragma unroll
        for (int r = 0; r < 4; ++r) {
            float e = __expf((sacc[nt][r] - mx[r]) * 0.125f);
            sacc[nt][r] = e;
            sm[r] += e;
        }
#pragma unroll
    for (int r = 0; r < 4; ++r) {
        sm[r] += __shfl_xor(sm[r], 1);
        sm[r] += __shfl_xor(sm[r], 2);
        sm[r] += __shfl_xor(sm[r], 4);
        sm[r] += __shfl_xor(sm[r], 8);
    }
    __syncthreads();  // K reads done; KP becomes P

    // write P into A-frag layout [key-plane][64 qrows][8]
#pragma unroll
    for (int nt = 0; nt < 25; ++nt)
#pragma unroll
        for (int r = 0; r < 4; ++r) {
            int colk = nt * 16 + l15;
            KP[((colk >> 3) * 64 + w * 16 + quad * 4 + r) * 8 + (colk & 7)] = f2bf(sacc[nt][r]);
        }
    // zero key planes 50,51 (keys 400..415)
    for (int idx = tid; idx < 1024; idx += 256) KP[25600 + idx] = 0;

    // phase 2: O = P V; V 64-row chunks transposed into QV via scalar gather
    f32x4 oacc[4];
#pragma unroll
    for (int dt = 0; dt < 4; ++dt) { oacc[dt][0] = 0; oacc[dt][1] = 0; oacc[dt][2] = 0; oacc[dt][3] = 0; }
    for (int kt = 0; kt < 13; ++kt) {
        if ((kt & 1) == 0) {
            __syncthreads();
            int v0r = (kt >> 1) * 64;
            for (int t = tid; t < 512; t += 256) {
                int d = t & 63, kq8 = t >> 6;
                const short* vp = qkv + (((size_t)(64 + 8 * h + (d >> 3))) * MR + rowb + v0r + kq8 * 8) * 8 + (d & 7);
                bf16x8 s8;
#pragma unroll
                for (int i = 0; i < 8; ++i) s8[i] = vp[i * 8];
                *reinterpret_cast<bf16x8*>(&QV[(kq8 * 64 + d) * 8]) = s8;
            }
            __syncthreads();
        }
        bf16x8 pa = *reinterpret_cast<const bf16x8*>(&KP[((kt * 4 + quad) * 64 + w * 16 + l15) * 8]);
#pragma unroll
        for (int dt = 0; dt < 4; ++dt) {
            bf16x8 vb = *reinterpret_cast<const bf16x8*>(&QV[(((kt & 1) * 4 + quad) * 64 + dt * 16 + l15) * 8]);
            oacc[dt] = __builtin_amdgcn_mfma_f32_16x16x32_bf16(pa, vb, oacc[dt], 0, 0, 0);
        }
    }
#pragma unroll
    for (int r = 0; r < 4; ++r) {
        int row = qt * 64 + w * 16 + quad * 4 + r;
        if (row >= NN) continue;
        float inv = 1.0f / sm[r];
#pragma unroll
        for (int dt = 0; dt < 4; ++dt) {
            int col = dt * 16 + l15;  // 0..63 within head
            Out[(((size_t)(8 * h + (col >> 3))) * MR + rowb + row) * 8 + (col & 7)] =
                f2bf(oacc[dt][r] * inv);
        }
    }
}

// ---------------------------------------------------------------------------
// fp32 [R x K] row-major -> P8 bf16 with K zero-padded to Kp, plane rows PR
// ---------------------------------------------------------------------------
__global__ void conv_p8(const float* __restrict__ src, short* __restrict__ dst,
                        int R, int K, int Kp, int PR)
{
    long long idx = (long long)blockIdx.x * 256 + threadIdx.x;
    if (idx >= (long long)R * Kp) return;
    int r = (int)(idx / Kp), k = (int)(idx - (long long)r * Kp);
    dst[((size_t)(k >> 3) * PR + r) * 8 + (k & 7)] = (k < K) ? f2bf(src[(size_t)r * K + k]) : (short)0;
}

// ---------------------------------------------------------------------------
__global__ void colsum_dinv(const float* __restrict__ sc, float* __restrict__ dinv)
{
    int b = blockIdx.y;
    int j = blockIdx.x * 256 + threadIdx.x;
    if (j >= NN) return;
    const float* p = sc + (size_t)b * NN * NN + j;
    float s = 0.0f;
    for (int i = 0; i < NN; ++i) s += p[(size_t)i * NN];
    dinv[b * NN + j] = (s > 0.0f) ? 1.0f / sqrtf(s) : 0.0f;
}

// ---------------------------------------------------------------------------
// scb[b]: P8 over j (56 planes x 512 rows_i x 8), = bf16(sc[i][j]), pads zero
// anT[b]: P8 over i (56 planes x 512 rows_j x 8), = bf16(dinv_j*sc[i][j]*dinv_i)
// ---------------------------------------------------------------------------
__global__ __launch_bounds__(256) void sc_prep(
    const float* __restrict__ sc, const float* __restrict__ dinv,
    short* __restrict__ scb, short* __restrict__ anT)
{
    __shared__ float tile[64][65];
    const int b = blockIdx.z;
    const int i0 = blockIdx.y * 64, j0 = blockIdx.x * 64;
    const int tid = threadIdx.x;
    const float* sb = sc + (size_t)b * NN * NN;
    short* scbb = scb + (size_t)b * 56 * 512 * 8;
    short* anTb = anT + (size_t)b * 56 * 512 * 8;
    for (int e = tid; e < 4096; e += 256) {
        int r = e >> 6, c = e & 63;
        int i = i0 + r, j = j0 + c;
        tile[r][c] = (i < NN && j < NN) ? sb[(size_t)i * NN + j] : 0.0f;
    }
    __syncthreads();
    for (int e = tid; e < 4096; e += 256) {
        int r = e >> 6, c = e & 63;
        int i = i0 + r, j = j0 + c;   // i,j < 448
        scbb[((size_t)(j >> 3) * 512 + i) * 8 + (j & 7)] = f2bf(tile[r][c]);
        float v = 0.0f;
        if (i < NN && j < NN) v = tile[r][c] * dinv[b * NN + i] * dinv[b * NN + j];
        anTb[((size_t)(i >> 3) * 512 + j) * 8 + (i & 7)] = f2bf(v);
    }
}

// ---------------------------------------------------------------------------
// Fused residual + LayerNorm over P8 (lane = row, 32 planes), two-pass
// ---------------------------------------------------------------------------
__global__ __launch_bounds__(256) void ln_res_p8(
    const short* __restrict__ x, const short* __restrict__ a,
    const float* __restrict__ g, const float* __restrict__ bb,
    short* __restrict__ y)
{
    __shared__ float gs[256], bs[256];
    const int tid = threadIdx.x;
    gs[tid] = g[tid]; bs[tid] = bb[tid];
    __syncthreads();
    const int row = blockIdx.x * 256 + tid;
    float sum = 0.0f, sq = 0.0f;
    for (int p = 0; p < 32; ++p) {
        bf16x8 xv = *reinterpret_cast<const bf16x8*>(x + ((size_t)p * MR + row) * 8);
        bf16x8 av = *reinterpret_cast<const bf16x8*>(a + ((size_t)p * MR + row) * 8);
#pragma unroll
        for (int e = 0; e < 8; ++e) {
            float v = bf2f(xv[e]) + bf2f(av[e]);
            sum += v; sq += v * v;
        }
    }
    float mu = sum * (1.0f / 256.0f);
    float var = sq * (1.0f / 256.0f) - mu * mu;
    float rstd = 1.0f / sqrtf(fmaxf(var, 0.0f) + 1e-5f);
    for (int p = 0; p < 32; ++p) {
        bf16x8 xv = *reinterpret_cast<const bf16x8*>(x + ((size_t)p * MR + row) * 8);
        bf16x8 av = *reinterpret_cast<const bf16x8*>(a + ((size_t)p * MR + row) * 8);
        bf16x8 o;
#pragma unroll
        for (int e = 0; e < 8; ++e) {
            float v = bf2f(xv[e]) + bf2f(av[e]);
            o[e] = f2bf((v - mu) * rstd * gs[p * 8 + e] + bs[p * 8 + e]);
        }
        *reinterpret_cast<bf16x8*>(y + ((size_t)p * MR + row) * 8) = o;
    }
}

// ---------------------------------------------------------------------------
// Classifier split-K: acc[b,o] += 0.5*(C1+C2)[b,k]*W1[o,k]; C1/C2 P8 bf16
// ---------------------------------------------------------------------------
#define CKC 512
__global__ __launch_bounds__(256) void cls_splitk(
    const short* __restrict__ C1, const short* __restrict__ C2,
    const float* __restrict__ W1, float* __restrict__ accum)
{
    __shared__ float As[16][65];
    __shared__ float Ws[16][65];
    const int n0 = blockIdx.x * 64;
    const int k0 = blockIdx.y * CKC;
    const int tid = threadIdx.x;
    const int ty = tid >> 4, tx = tid & 15;
    const int lk = tid & 15, lr = tid >> 4;
    float acc[4][4] = {};
    for (int kc = 0; kc < CKC; kc += 16) {
        int kb = k0 + kc;
#pragma unroll
        for (int i = 0; i < 4; ++i) {
            int r = lr + 16 * i;
            int k = kb + lk;
            int j = k >> 8, e = k & 255;
            size_t ad = ((size_t)(e >> 3) * MR + r * 400 + j) * 8 + (e & 7);
            As[lk][r] = 0.5f * (bf2f(C1[ad]) + bf2f(C2[ad]));
            Ws[lk][r] = W1[(size_t)(n0 + r) * 102400 + k];
        }
        __syncthreads();
#pragma unroll
        for (int kk = 0; kk < 16; ++kk) {
            float a[4], b[4];
#pragma unroll
            for (int i = 0; i < 4; ++i) a[i] = As[kk][ty * 4 + i];
#pragma unroll
            for (int j = 0; j < 4; ++j) b[j] = Ws[kk][tx * 4 + j];
#pragma unroll
            for (int i = 0; i < 4; ++i)
#pragma unroll
                for (int j = 0; j < 4; ++j)
                    acc[i][j] = fmaf(a[i], b[j], acc[i][j]);
        }
        __syncthreads();
    }
#pragma unroll
    for (int i = 0; i < 4; ++i)
#pragma unroll
        for (int j = 0; j < 4; ++j)
            atomicAdd(&accum[(ty * 4 + i) * 128 + n0 + tx * 4 + j], acc[i][j]);
}

__global__ void zero_buf(float* p, int n)
{
    int i = blockIdx.x * 256 + threadIdx.x;
    if (i < n) p[i] = 0.0f;
}

__global__ void logits_final(
    const float* __restrict__ clsh, const float* __restrict__ b1,
    const float* __restrict__ w2, const float* __restrict__ b2,
    float* __restrict__ out)
{
    __shared__ float t[128];
    int b = blockIdx.x;
    int tid = threadIdx.x;
    t[tid] = fmaxf(clsh[b * 128 + tid] + b1[tid], 0.0f);
    __syncthreads();
    if (tid < 2) {
        float s = b2[tid];
        for (int o = 0; o < 128; ++o) s += t[o] * w2[tid * 128 + o];
        out[b * 2 + tid] = s;
    }
}

// ---------------------------------------------------------------------------
extern "C" void kernel_launch(void* const* d_in, const int* in_sizes, int n_in,
                              void* d_out, int out_size, void* d_ws, size_t ws_size,
                              hipStream_t stream)
{
    const float* fc        = (const float*)d_in[0];
    const float* sc        = (const float*)d_in[1];
    const float* proj_w    = (const float*)d_in[2];
    const float* proj_b    = (const float*)d_in[3];
    const float* enc_qkv_w = (const float*)d_in[4];
    const float* enc_qkv_b = (const float*)d_in[5];
    const float* enc_out_w = (const float*)d_in[6];
    const float* enc_out_b = (const float*)d_in[7];
    const float* enc_l1_w  = (const float*)d_in[8];
    const float* enc_l1_b  = (const float*)d_in[9];
    const float* enc_l2_w  = (const float*)d_in[10];
    const float* enc_l2_b  = (const float*)d_in[11];
    const float* enc_n1_g  = (const float*)d_in[12];
    const float* enc_n1_b  = (const float*)d_in[13];
    const float* enc_n2_g  = (const float*)d_in[14];
    const float* enc_n2_b  = (const float*)d_in[15];
    const float* gcn_w1    = (const float*)d_in[16];
    const float* gcn_b1    = (const float*)d_in[17];
    const float* gcn_w2    = (const float*)d_in[18];
    const float* gcn_b2    = (const float*)d_in[19];
    const float* ca1_qkv_w = (const float*)d_in[20];
    const float* ca1_qkv_b = (const float*)d_in[21];
    const float* ca1_out_w = (const float*)d_in[22];
    const float* ca1_out_b = (const float*)d_in[23];
    const float* ca1_n_g   = (const float*)d_in[24];
    const float* ca1_n_b   = (const float*)d_in[25];
    const float* ca2_qkv_w = (const float*)d_in[26];
    const float* ca2_qkv_b = (const float*)d_in[27];
    const float* ca2_out_w = (const float*)d_in[28];
    const float* ca2_out_b = (const float*)d_in[29];
    const float* ca2_n_g   = (const float*)d_in[30];
    const float* ca2_n_b   = (const float*)d_in[31];
    const float* cls_w1    = (const float*)d_in[32];
    const float* cls_b1    = (const float*)d_in[33];
    const float* cls_w2    = (const float*)d_in[34];
    const float* cls_b2    = (const float*)d_in[35];

    char* wsb = (char*)d_ws;
    size_t off = 0;
    auto alloc = [&](size_t bytes) { char* r = wsb + off; off += (bytes + 255) & ~(size_t)255; return r; };
    short* bufBig = (short*)alloc((size_t)MR * 1024 * 2);          // 128 planes x MR
    short* fcb    = (short*)alloc((size_t)56 * MR * 8 * 2);        // P8 K448
    short* anT    = (short*)alloc((size_t)NB * 56 * 512 * 8 * 2);
    short* bufH   = (short*)alloc((size_t)32 * MR * 8 * 2);
    short* bufA   = (short*)alloc((size_t)32 * MR * 8 * 2);
    short* bufB   = (short*)alloc((size_t)32 * MR * 8 * 2);
    short* bufC   = (short*)alloc((size_t)32 * MR * 8 * 2);
    short* bufZS  = (short*)alloc((size_t)32 * MR * 8 * 2);
    short* projwb = (short*)alloc((size_t)56 * 256 * 8 * 2);
    short* qkvwb  = (short*)alloc((size_t)32 * 1536 * 8 * 2);
    short* outwb  = (short*)alloc((size_t)32 * 512 * 8 * 2);
    short* l1wb   = (short*)alloc((size_t)32 * 2048 * 8 * 2);
    short* l2wb   = (short*)alloc((size_t)128 * 512 * 8 * 2);
    short* gw1b   = (short*)alloc((size_t)56 * 256 * 8 * 2);
    short* gw2b   = (short*)alloc((size_t)32 * 256 * 8 * 2);
    short* c1qb   = (short*)alloc((size_t)32 * 768 * 8 * 2);
    short* c1ob   = (short*)alloc((size_t)32 * 256 * 8 * 2);
    short* c2qb   = (short*)alloc((size_t)32 * 768 * 8 * 2);
    short* c2ob   = (short*)alloc((size_t)32 * 256 * 8 * 2);
    float* dinv   = (float*)alloc((size_t)MR * 4);
    float* clsh   = (float*)alloc((size_t)NB * 128 * 4);
    // GCN temporaries aliased into bufBig (dead between encoder and CA phases)
    short* scb = bufBig;                                   // [64][56][512][8]
    short* XT1 = bufBig + (size_t)64 * 56 * 512 * 8;       // [64][56][256][8]
    short* h1  = bufBig;                                   // [64][32][512][8] (after scb dead)
    short* XT2 = XT1;                                      // reuse (after XT1 dead)

    dim3 blk(256);
    auto cgrid = [](long long n) { return dim3((unsigned)((n + 255) / 256)); };

    // ---- conversions to P8 ----
    conv_p8<<<cgrid((long long)MR * 448), blk, 0, stream>>>(fc, fcb, MR, 400, 448, MR);
    conv_p8<<<cgrid(256 * 448), blk, 0, stream>>>(proj_w, projwb, 256, 400, 448, 256);
    conv_p8<<<cgrid(1536 * 256), blk, 0, stream>>>(enc_qkv_w, qkvwb, 1536, 256, 256, 1536);
    conv_p8<<<cgrid(512 * 256), blk, 0, stream>>>(enc_out_w, outwb, 512, 256, 256, 512);
    conv_p8<<<cgrid(2048 * 256), blk, 0, stream>>>(enc_l1_w, l1wb, 2048, 256, 256, 2048);
    conv_p8<<<cgrid(512 * 1024), blk, 0, stream>>>(enc_l2_w, l2wb, 512, 1024, 1024, 512);
    conv_p8<<<cgrid(256 * 448), blk, 0, stream>>>(gcn_w1, gw1b, 256, 400, 448, 256);
    conv_p8<<<cgrid(256 * 256), blk, 0, stream>>>(gcn_w2, gw2b, 256, 256, 256, 256);
    conv_p8<<<cgrid(768 * 256), blk, 0, stream>>>(ca1_qkv_w, c1qb, 768, 256, 256, 768);
    conv_p8<<<cgrid(256 * 256), blk, 0, stream>>>(ca1_out_w, c1ob, 256, 256, 256, 256);
    conv_p8<<<cgrid(768 * 256), blk, 0, stream>>>(ca2_qkv_w, c2qb, 768, 256, 256, 768);
    conv_p8<<<cgrid(256 * 256), blk, 0, stream>>>(ca2_out_w, c2ob, 256, 256, 256, 256);

    // ---- FC branch ----
    gemm_p8<<<dim3(2, 200, 1), blk, 0, stream>>>(
        fcb, MR, 0, projwb, 256, 0, proj_b, bufH, MR, 0, 0, MR, 256, 256, 448, 0);
    for (int l = 0; l < 2; ++l) {
        gemm_p8<<<dim3(6, 200, 1), blk, 0, stream>>>(
            bufH, MR, 0, qkvwb + (size_t)l * 768 * 8, 1536, 0, enc_qkv_b + l * 768,
            bufBig, MR, 0, 0, MR, 768, 768, 256, 0);
        attn_p8<<<dim3(7, NHH, NB), blk, 0, stream>>>(bufBig, bufA);
        gemm_p8<<<dim3(2, 200, 1), blk, 0, stream>>>(
            bufA, MR, 0, outwb + (size_t)l * 256 * 8, 512, 0, enc_out_b + l * 256,
            bufB, MR, 0, 0, MR, 256, 256, 256, 0);
        ln_res_p8<<<100, blk, 0, stream>>>(bufH, bufB, enc_n1_g + l * DD, enc_n1_b + l * DD, bufH);
        gemm_p8<<<dim3(8, 200, 1), blk, 0, stream>>>(
            bufH, MR, 0, l1wb + (size_t)l * 1024 * 8, 2048, 0, enc_l1_b + l * 1024,
            bufBig, MR, 0, 0, MR, 1024, 1024, 256, 1);
        gemm_p8<<<dim3(2, 200, 1), blk, 0, stream>>>(
            bufBig, MR, 0, l2wb + (size_t)l * 256 * 8, 512, 0, enc_l2_b + l * 256,
            bufA, MR, 0, 0, MR, 256, 256, 1024, 0);
        ln_res_p8<<<100, blk, 0, stream>>>(bufH, bufA, enc_n2_g + l * DD, enc_n2_b + l * DD, bufH);
    }

    // ---- GCN branch (P8 GEMMs; temps aliased into bufBig) ----
    colsum_dinv<<<dim3(2, NB), blk, 0, stream>>>(sc, dinv);
    sc_prep<<<dim3(7, 7, NB), blk, 0, stream>>>(sc, dinv, scb, anT);
    // XT1[b][d][i] = sum_j gw1[d][j]*sc[b][i][j]
    gemm_p8<<<dim3(4, 2, NB), blk, 0, stream>>>(
        gw1b, 256, 0, scb, 512, 56LL * 512 * 8, nullptr,
        XT1, 256, 0, 56LL * 256 * 8, 256, 400, 448, 448, 0);
    // h1[b][j][d] = relu(sum_i anT[b][j][i]*XT1[b][d][i] + b1)
    gemm_p8<<<dim3(2, 4, NB), blk, 0, stream>>>(
        anT, 512, 56LL * 512 * 8, XT1, 256, 56LL * 256 * 8, gcn_b1,
        h1, 512, 0, 32LL * 512 * 8, 400, 256, 256, 448, 1);
    // XT2[b][e][i] = sum_d gw2[e][d]*h1[b][i][d]
    gemm_p8<<<dim3(4, 2, NB), blk, 0, stream>>>(
        gw2b, 256, 0, h1, 512, 32LL * 512 * 8, nullptr,
        XT2, 256, 0, 56LL * 256 * 8, 256, 400, 448, 256, 0);
    // Z_S[b][j][e] = sum_i anT[b][j][i]*XT2[b][e][i] + b2
    gemm_p8<<<dim3(2, 4, NB), blk, 0, stream>>>(
        anT, 512, 56LL * 512 * 8, XT2, 256, 56LL * 256 * 8, gcn_b2,
        bufZS, MR, 400, 0, 400, 256, 256, 448, 0);

    // ---- Cross attention 1: Q = Z_F, KV = Z_S ----
    gemm_p8<<<dim3(2, 200, 1), blk, 0, stream>>>(
        bufH, MR, 0, c1qb, 768, 0, ca1_qkv_b, bufBig, MR, 0, 0, MR, 256, 256, 256, 0);
    gemm_p8<<<dim3(4, 200, 1), blk, 0, stream>>>(
        bufZS, MR, 0, c1qb + 256 * 8, 768, 0, ca1_qkv_b + 256,
        bufBig + (size_t)32 * MR * 8, MR, 0, 0, MR, 512, 512, 256, 0);
    attn_p8<<<dim3(7, NHH, NB), blk, 0, stream>>>(bufBig, bufA);
    gemm_p8<<<dim3(2, 200, 1), blk, 0, stream>>>(
        bufA, MR, 0, c1ob, 256, 0, ca1_out_b, bufB, MR, 0, 0, MR, 256, 256, 256, 0);
    ln_res_p8<<<100, blk, 0, stream>>>(bufH, bufB, ca1_n_g, ca1_n_b, bufC);

    // ---- Cross attention 2: Q = Z_S, KV = Z_F ----
    gemm_p8<<<dim3(2, 200, 1), blk, 0, stream>>>(
        bufZS, MR, 0, c2qb, 768, 0, ca2_qkv_b, bufBig, MR, 0, 0, MR, 256, 256, 256, 0);
    gemm_p8<<<dim3(4, 200, 1), blk, 0, stream>>>(
        bufH, MR, 0, c2qb + 256 * 8, 768, 0, ca2_qkv_b + 256,
        bufBig + (size_t)32 * MR * 8, MR, 0, 0, MR, 512, 512, 256, 0);
    attn_p8<<<dim3(7, NHH, NB), blk, 0, stream>>>(bufBig, bufA);
    gemm_p8<<<dim3(2, 200, 1), blk, 0, stream>>>(
        bufA, MR, 0, c2ob, 256, 0, ca2_out_b, bufB, MR, 0, 0, MR, 256, 256, 256, 0);
    ln_res_p8<<<100, blk, 0, stream>>>(bufZS, bufB, ca2_n_g, ca2_n_b, bufZS);

    // ---- Classifier ----
    zero_buf<<<cgrid(NB * 128), blk, 0, stream>>>(clsh, NB * 128);
    cls_splitk<<<dim3(2, 200), blk, 0, stream>>>(bufC, bufZS, cls_w1, clsh);
    logits_final<<<NB, 128, 0, stream>>>(clsh, cls_b1, cls_w2, cls_b2, (float*)d_out);
}

// Round 5
// 1372.722 us; speedup vs baseline: 1.0689x; 1.0689x over previous
//
#include <hip/hip_runtime.h>
#include <math.h>

// Problem constants
#define NB   64
#define NN   400
#define DD   256
#define NHH  4
#define HDD  64
#define MR   25600            // NB*NN
#define KP448 448             // 400 padded to multiple of 64

typedef __attribute__((ext_vector_type(8))) short bf16x8;
typedef __attribute__((ext_vector_type(4))) float f32x4;

__device__ __forceinline__ short f2bf(float x) {
    union { float f; unsigned u; } v; v.f = x;
    return (short)((v.u + 0x7FFFu + ((v.u >> 16) & 1u)) >> 16);
}
__device__ __forceinline__ float bf2f(short s) {
    union { unsigned u; float f; } v; v.u = ((unsigned)(unsigned short)s) << 16;
    return v.f;
}
// async global->LDS, 16 B/lane; LDS dest = wave-uniform base + lane*16
__device__ __forceinline__ void gl_lds16(const void* g, void* l) {
    __builtin_amdgcn_global_load_lds(
        (const __attribute__((address_space(1))) unsigned*)g,
        (__attribute__((address_space(3))) unsigned*)l, 16, 0, 0);
}

// ---------------------------------------------------------------------------
// P8 layout: element (row, k) of a [rows x K] tensor lives at
//   ((k>>3)*rows + row)*8 + (k&7)      (bf16 shorts)
// = the 16x16x32 MFMA fragment layout; staging is contiguous 1 KiB bursts.
// ---------------------------------------------------------------------------

// bf16 GEMM, 128x128 tile, BK=64, double-buffered LDS prefetch.
// C(m,n) = act(sum_k A(m,k)*B(n,k) + bias[n]); C written in P8 (plane=n>>3).
__global__ __launch_bounds__(256) void gemm_p8(
    const short* __restrict__ A, int arows, long long sA,
    const short* __restrict__ B, int brows, long long sB,
    const float* __restrict__ bias,
    short* __restrict__ C, int crows, int crz, long long sCe,
    int M, int N, int Npad, int K, int relu)
{
    __shared__ short Al[2][8 * 128 * 8];
    __shared__ short Bl[2][8 * 128 * 8];
    const int tid = threadIdx.x;
    const int z = blockIdx.z;
    const int m0 = blockIdx.y * 128, n0 = blockIdx.x * 128;
    const short* Ab = A + (size_t)z * sA;
    const short* Bb = B + (size_t)z * sB;

    const int w = tid >> 6, lane = tid & 63;
    const int quad = lane >> 4, l15 = lane & 15;
    const int wm = w & 1, wn = w >> 1;

    f32x4 acc[4][4] = {};

    const int KT = K >> 6;
    // stage tile kt into buffer buf (each wave: 8 x 1KiB bursts)
    auto stage = [&](int buf, int kt) {
        const int gp0 = kt << 3;
#pragma unroll
        for (int pp = 0; pp < 2; ++pp) {
            const int p = w + pp * 4;
            gl_lds16(Ab + ((size_t)(gp0 + p) * arows + m0 + lane) * 8,      &Al[buf][(p * 128) * 8]);
            gl_lds16(Ab + ((size_t)(gp0 + p) * arows + m0 + 64 + lane) * 8, &Al[buf][(p * 128 + 64) * 8]);
            gl_lds16(Bb + ((size_t)(gp0 + p) * brows + n0 + lane) * 8,      &Bl[buf][(p * 128) * 8]);
            gl_lds16(Bb + ((size_t)(gp0 + p) * brows + n0 + 64 + lane) * 8, &Bl[buf][(p * 128 + 64) * 8]);
        }
    };
    stage(0, 0);
    __syncthreads();
    for (int kt = 0; kt < KT; ++kt) {
        const int cur = kt & 1;
        if (kt + 1 < KT) stage(cur ^ 1, kt + 1);
#pragma unroll
        for (int kb = 0; kb < 2; ++kb) {
            bf16x8 af[4], bfr[4];
#pragma unroll
            for (int mi = 0; mi < 4; ++mi)
                af[mi] = *reinterpret_cast<const bf16x8*>(
                    &Al[cur][((kb * 4 + quad) * 128 + wm * 64 + mi * 16 + l15) * 8]);
#pragma unroll
            for (int ni = 0; ni < 4; ++ni)
                bfr[ni] = *reinterpret_cast<const bf16x8*>(
                    &Bl[cur][((kb * 4 + quad) * 128 + wn * 64 + ni * 16 + l15) * 8]);
#pragma unroll
            for (int mi = 0; mi < 4; ++mi)
#pragma unroll
                for (int ni = 0; ni < 4; ++ni)
                    acc[mi][ni] = __builtin_amdgcn_mfma_f32_16x16x32_bf16(af[mi], bfr[ni], acc[mi][ni], 0, 0, 0);
        }
        __syncthreads();   // publishes buf cur^1 (vmcnt drain) + protects reuse
    }

    short* Cbz = C + (size_t)z * sCe;
    const long long zr = (long long)z * crz;
#pragma unroll
    for (int mi = 0; mi < 4; ++mi) {
#pragma unroll
        for (int r = 0; r < 4; ++r) {
            int row = m0 + wm * 64 + mi * 16 + quad * 4 + r;
            if (row >= M) continue;
#pragma unroll
            for (int ni = 0; ni < 4; ++ni) {
                int col = n0 + wn * 64 + ni * 16 + l15;
                if (col >= Npad) continue;
                float v = 0.0f;
                if (col < N) {
                    v = acc[mi][ni][r];
                    if (bias) v += bias[col];
                    if (relu) v = fmaxf(v, 0.0f);
                }
                Cbz[((size_t)(col >> 3) * crows + zr + row) * 8 + (col & 7)] = f2bf(v);
            }
        }
    }
}

// ---------------------------------------------------------------------------
// Attention over P8 QKV buffer (96 planes x MR rows x 8).
// Q: planes 8h..8h+7 ; K: 32+8h.. ; V: 64+8h..  Out -> P8 (32 planes x MR).
// ---------------------------------------------------------------------------
__global__ __launch_bounds__(256) void attn_p8(
    const short* __restrict__ qkv, short* __restrict__ Out)
{
    __shared__ short KP[8 * 448 * 8];   // K planes [8][448][8]; later P [52][64][8]
    __shared__ short QV[8 * 64 * 8];    // Q [8][64][8]; later V chunks [8][64][8]
    const int qt = blockIdx.x, h = blockIdx.y, b = blockIdx.z;
    const int tid = threadIdx.x;
    const int w = tid >> 6, lane = tid & 63;
    const int quad = lane >> 4, l15 = lane & 15;
    const size_t rowb = (size_t)b * NN;

    for (int j = w; j < 8; j += 4)
        gl_lds16(qkv + (((size_t)(8 * h + j)) * MR + rowb + qt * 64 + lane) * 8, &QV[(j * 64) * 8]);
    for (int t = w; t < 56; t += 4) {
        int j = t / 7, c = t - j * 7;
        gl_lds16(qkv + (((size_t)(32 + 8 * h + j)) * MR + rowb + c * 64 + lane) * 8,
                 &KP[(j * 448 + c * 64) * 8]);
    }
    __syncthreads();

    bf16x8 aq0 = *reinterpret_cast<const bf16x8*>(&QV[(quad * 64 + w * 16 + l15) * 8]);
    bf16x8 aq1 = *reinterpret_cast<const bf16x8*>(&QV[((4 + quad) * 64 + w * 16 + l15) * 8]);
    f32x4 sacc[25];
#pragma unroll
    for (int nt = 0; nt < 25; ++nt) { sacc[nt][0] = 0; sacc[nt][1] = 0; sacc[nt][2] = 0; sacc[nt][3] = 0; }
#pragma unroll
    for (int nt = 0; nt < 25; ++nt) {
        bf16x8 b0 = *reinterpret_cast<const bf16x8*>(&KP[(quad * 448 + nt * 16 + l15) * 8]);
        bf16x8 b1 = *reinterpret_cast<const bf16x8*>(&KP[((4 + quad) * 448 + nt * 16 + l15) * 8]);
        sacc[nt] = __builtin_amdgcn_mfma_f32_16x16x32_bf16(aq0, b0, sacc[nt], 0, 0, 0);
        sacc[nt] = __builtin_amdgcn_mfma_f32_16x16x32_bf16(aq1, b1, sacc[nt], 0, 0, 0);
    }

    float mx[4] = {-3e38f, -3e38f, -3e38f, -3e38f}, sm[4] = {0, 0, 0, 0};
#pragma unroll
    for (int nt = 0; nt < 25; ++nt)
#pragma unroll
        for (int r = 0; r < 4; ++r) mx[r] = fmaxf(mx[r], sacc[nt][r]);
#pragma unroll
    for (int r = 0; r < 4; ++r) {
        mx[r] = fmaxf(mx[r], __shfl_xor(mx[r], 1));
        mx[r] = fmaxf(mx[r], __shfl_xor(mx[r], 2));
        mx[r] = fmaxf(mx[r], __shfl_xor(mx[r], 4));
        mx[r] = fmaxf(mx[r], __shfl_xor(mx[r], 8));
    }
#pragma unroll
    for (int nt = 0; nt < 25; ++nt)
#pragma unroll
        for (int r = 0; r < 4; ++r) {
            float e = __expf((sacc[nt][r] - mx[r]) * 0.125f);
            sacc[nt][r] = e;
            sm[r] += e;
        }
#pragma unroll
    for (int r = 0; r < 4; ++r) {
        sm[r] += __shfl_xor(sm[r], 1);
        sm[r] += __shfl_xor(sm[r], 2);
        sm[r] += __shfl_xor(sm[r], 4);
        sm[r] += __shfl_xor(sm[r], 8);
    }
    __syncthreads();

#pragma unroll
    for (int nt = 0; nt < 25; ++nt)
#pragma unroll
        for (int r = 0; r < 4; ++r) {
            int colk = nt * 16 + l15;
            KP[((colk >> 3) * 64 + w * 16 + quad * 4 + r) * 8 + (colk & 7)] = f2bf(sacc[nt][r]);
        }
    for (int idx = tid; idx < 1024; idx += 256) KP[25600 + idx] = 0;

    f32x4 oacc[4];
#pragma unroll
    for (int dt = 0; dt < 4; ++dt) { oacc[dt][0] = 0; oacc[dt][1] = 0; oacc[dt][2] = 0; oacc[dt][3] = 0; }
    for (int kt = 0; kt < 13; ++kt) {
        if ((kt & 1) == 0) {
            __syncthreads();
            int v0r = (kt >> 1) * 64;
            for (int t = tid; t < 512; t += 256) {
                int d = t & 63, kq8 = t >> 6;
                const short* vp = qkv + (((size_t)(64 + 8 * h + (d >> 3))) * MR + rowb + v0r + kq8 * 8) * 8 + (d & 7);
                bf16x8 s8;
#pragma unroll
                for (int i = 0; i < 8; ++i) s8[i] = vp[i * 8];
                *reinterpret_cast<bf16x8*>(&QV[(kq8 * 64 + d) * 8]) = s8;
            }
            __syncthreads();
        }
        bf16x8 pa = *reinterpret_cast<const bf16x8*>(&KP[((kt * 4 + quad) * 64 + w * 16 + l15) * 8]);
#pragma unroll
        for (int dt = 0; dt < 4; ++dt) {
            bf16x8 vb = *reinterpret_cast<const bf16x8*>(&QV[(((kt & 1) * 4 + quad) * 64 + dt * 16 + l15) * 8]);
            oacc[dt] = __builtin_amdgcn_mfma_f32_16x16x32_bf16(pa, vb, oacc[dt], 0, 0, 0);
        }
    }
#pragma unroll
    for (int r = 0; r < 4; ++r) {
        int row = qt * 64 + w * 16 + quad * 4 + r;
        if (row >= NN) continue;
        float inv = 1.0f / sm[r];
#pragma unroll
        for (int dt = 0; dt < 4; ++dt) {
            int col = dt * 16 + l15;
            Out[(((size_t)(8 * h + (col >> 3))) * MR + rowb + row) * 8 + (col & 7)] =
                f2bf(oacc[dt][r] * inv);
        }
    }
}

// ---------------------------------------------------------------------------
// fp32 [R x K] row-major -> P8 bf16 with K zero-padded to Kp, plane rows PR
// ---------------------------------------------------------------------------
__global__ void conv_p8(const float* __restrict__ src, short* __restrict__ dst,
                        int R, int K, int Kp, int PR)
{
    long long idx = (long long)blockIdx.x * 256 + threadIdx.x;
    if (idx >= (long long)R * Kp) return;
    int r = (int)(idx / Kp), k = (int)(idx - (long long)r * Kp);
    dst[((size_t)(k >> 3) * PR + r) * 8 + (k & 7)] = (k < K) ? f2bf(src[(size_t)r * K + k]) : (short)0;
}

// ---------------------------------------------------------------------------
__global__ void colsum_dinv(const float* __restrict__ sc, float* __restrict__ dinv)
{
    int b = blockIdx.y;
    int j = blockIdx.x * 256 + threadIdx.x;
    if (j >= NN) return;
    const float* p = sc + (size_t)b * NN * NN + j;
    float s = 0.0f;
    for (int i = 0; i < NN; ++i) s += p[(size_t)i * NN];
    dinv[b * NN + j] = (s > 0.0f) ? 1.0f / sqrtf(s) : 0.0f;
}

// ---------------------------------------------------------------------------
// scb[b]: P8 over j (56 planes x 512 rows_i x 8) = bf16(sc[i][j]); pads zero
// anT[b]: P8 over i (56 planes x 512 rows_j x 8) = bf16(dinv_j*sc[i][j]*dinv_i)
// ---------------------------------------------------------------------------
__global__ __launch_bounds__(256) void sc_prep(
    const float* __restrict__ sc, const float* __restrict__ dinv,
    short* __restrict__ scb, short* __restrict__ anT)
{
    __shared__ float tile[64][65];
    const int b = blockIdx.z;
    const int i0 = blockIdx.y * 64, j0 = blockIdx.x * 64;
    const int tid = threadIdx.x;
    const float* sb = sc + (size_t)b * NN * NN;
    short* scbb = scb + (size_t)b * 56 * 512 * 8;
    short* anTb = anT + (size_t)b * 56 * 512 * 8;
    for (int e = tid; e < 4096; e += 256) {
        int r = e >> 6, c = e & 63;
        int i = i0 + r, j = j0 + c;
        tile[r][c] = (i < NN && j < NN) ? sb[(size_t)i * NN + j] : 0.0f;
    }
    __syncthreads();
    for (int e = tid; e < 4096; e += 256) {
        int r = e >> 6, c = e & 63;
        int i = i0 + r, j = j0 + c;
        scbb[((size_t)(j >> 3) * 512 + i) * 8 + (j & 7)] = f2bf(tile[r][c]);
        float v = 0.0f;
        if (i < NN && j < NN) v = tile[r][c] * dinv[b * NN + i] * dinv[b * NN + j];
        anTb[((size_t)(i >> 3) * 512 + j) * 8 + (i & 7)] = f2bf(v);
    }
}

// ---------------------------------------------------------------------------
// Fused residual + LayerNorm over P8. Block = 64 rows; thread (row, quarter).
// Coalesced: for fixed plane, 64 lanes read 64 consecutive rows (1 KiB).
// ---------------------------------------------------------------------------
__global__ __launch_bounds__(256) void ln_res_p8(
    const short* __restrict__ x, const short* __restrict__ a,
    const float* __restrict__ g, const float* __restrict__ bb,
    short* __restrict__ y)
{
    __shared__ float gs[256], bs[256];
    __shared__ float red[2][4][64];
    const int tid = threadIdx.x;
    gs[tid] = g[tid]; bs[tid] = bb[tid];
    const int rl = tid & 63;           // row within block
    const int part = tid >> 6;         // plane quarter (8 planes)
    const int row = blockIdx.x * 64 + rl;
    float sum = 0.0f, sq = 0.0f;
    float vv[8][8];
#pragma unroll
    for (int i = 0; i < 8; ++i) {
        int p = part * 8 + i;
        bf16x8 xv = *reinterpret_cast<const bf16x8*>(x + ((size_t)p * MR + row) * 8);
        bf16x8 av = *reinterpret_cast<const bf16x8*>(a + ((size_t)p * MR + row) * 8);
#pragma unroll
        for (int e = 0; e < 8; ++e) {
            float v = bf2f(xv[e]) + bf2f(av[e]);
            vv[i][e] = v;
            sum += v; sq += v * v;
        }
    }
    red[0][part][rl] = sum; red[1][part][rl] = sq;
    __syncthreads();
    sum = red[0][0][rl] + red[0][1][rl] + red[0][2][rl] + red[0][3][rl];
    sq  = red[1][0][rl] + red[1][1][rl] + red[1][2][rl] + red[1][3][rl];
    float mu = sum * (1.0f / 256.0f);
    float var = sq * (1.0f / 256.0f) - mu * mu;
    float rstd = 1.0f / sqrtf(fmaxf(var, 0.0f) + 1e-5f);
#pragma unroll
    for (int i = 0; i < 8; ++i) {
        int p = part * 8 + i;
        bf16x8 o;
#pragma unroll
        for (int e = 0; e < 8; ++e)
            o[e] = f2bf((vv[i][e] - mu) * rstd * gs[p * 8 + e] + bs[p * 8 + e]);
        *reinterpret_cast<bf16x8*>(y + ((size_t)p * MR + row) * 8) = o;
    }
}

// ---------------------------------------------------------------------------
// Z_joint pack: Zr[b][j*256 + p*8 + e] = bf16(0.5*(C1+C2)) from P8 inputs.
// grid (100, 32): plane = blockIdx.y, rows m = blockIdx.x*256+tid (coalesced).
// ---------------------------------------------------------------------------
__global__ __launch_bounds__(256) void zjoint_pack(
    const short* __restrict__ C1, const short* __restrict__ C2,
    short* __restrict__ Zr)
{
    const int p = blockIdx.y;
    const int m = blockIdx.x * 256 + threadIdx.x;
    bf16x8 a = *reinterpret_cast<const bf16x8*>(C1 + ((size_t)p * MR + m) * 8);
    bf16x8 b = *reinterpret_cast<const bf16x8*>(C2 + ((size_t)p * MR + m) * 8);
    bf16x8 o;
#pragma unroll
    for (int e = 0; e < 8; ++e) o[e] = f2bf(0.5f * (bf2f(a[e]) + bf2f(b[e])));
    int bb = m / 400, j = m - bb * 400;
    *reinterpret_cast<bf16x8*>(Zr + (size_t)bb * 102400 + (size_t)j * 256 + p * 8) = o;
}

// ---------------------------------------------------------------------------
// Classifier split-K, fully coalesced: A = Zr bf16 [64][102400] row-major,
// W1 fp32 [128][102400]. grid (2 n-halves, 100 k-chunks of 1024).
// ---------------------------------------------------------------------------
#define CKC 1024
__global__ __launch_bounds__(256) void cls_splitk(
    const short* __restrict__ Zr, const float* __restrict__ W1,
    float* __restrict__ accum)
{
    __shared__ float As[16][65];
    __shared__ float Ws[16][65];
    const int n0 = blockIdx.x * 64;
    const int k0 = blockIdx.y * CKC;
    const int tid = threadIdx.x;
    const int ty = tid >> 4, tx = tid & 15;
    const int lk = tid & 15, lr = tid >> 4;
    float acc[4][4] = {};
    for (int kc = 0; kc < CKC; kc += 16) {
        int kb = k0 + kc;
#pragma unroll
        for (int i = 0; i < 4; ++i) {
            int r = lr + 16 * i;
            As[lk][r] = bf2f(Zr[(size_t)r * 102400 + kb + lk]);
            Ws[lk][r] = W1[(size_t)(n0 + r) * 102400 + kb + lk];
        }
        __syncthreads();
#pragma unroll
        for (int kk = 0; kk < 16; ++kk) {
            float a[4], b[4];
#pragma unroll
            for (int i = 0; i < 4; ++i) a[i] = As[kk][ty * 4 + i];
#pragma unroll
            for (int j = 0; j < 4; ++j) b[j] = Ws[kk][tx * 4 + j];
#pragma unroll
            for (int i = 0; i < 4; ++i)
#pragma unroll
                for (int j = 0; j < 4; ++j)
                    acc[i][j] = fmaf(a[i], b[j], acc[i][j]);
        }
        __syncthreads();
    }
#pragma unroll
    for (int i = 0; i < 4; ++i)
#pragma unroll
        for (int j = 0; j < 4; ++j)
            atomicAdd(&accum[(ty * 4 + i) * 128 + n0 + tx * 4 + j], acc[i][j]);
}

__global__ void zero_buf(float* p, int n)
{
    int i = blockIdx.x * 256 + threadIdx.x;
    if (i < n) p[i] = 0.0f;
}

__global__ void logits_final(
    const float* __restrict__ clsh, const float* __restrict__ b1,
    const float* __restrict__ w2, const float* __restrict__ b2,
    float* __restrict__ out)
{
    __shared__ float t[128];
    int b = blockIdx.x;
    int tid = threadIdx.x;
    t[tid] = fmaxf(clsh[b * 128 + tid] + b1[tid], 0.0f);
    __syncthreads();
    if (tid < 2) {
        float s = b2[tid];
        for (int o = 0; o < 128; ++o) s += t[o] * w2[tid * 128 + o];
        out[b * 2 + tid] = s;
    }
}

// ---------------------------------------------------------------------------
extern "C" void kernel_launch(void* const* d_in, const int* in_sizes, int n_in,
                              void* d_out, int out_size, void* d_ws, size_t ws_size,
                              hipStream_t stream)
{
    const float* fc        = (const float*)d_in[0];
    const float* sc        = (const float*)d_in[1];
    const float* proj_w    = (const float*)d_in[2];
    const float* proj_b    = (const float*)d_in[3];
    const float* enc_qkv_w = (const float*)d_in[4];
    const float* enc_qkv_b = (const float*)d_in[5];
    const float* enc_out_w = (const float*)d_in[6];
    const float* enc_out_b = (const float*)d_in[7];
    const float* enc_l1_w  = (const float*)d_in[8];
    const float* enc_l1_b  = (const float*)d_in[9];
    const float* enc_l2_w  = (const float*)d_in[10];
    const float* enc_l2_b  = (const float*)d_in[11];
    const float* enc_n1_g  = (const float*)d_in[12];
    const float* enc_n1_b  = (const float*)d_in[13];
    const float* enc_n2_g  = (const float*)d_in[14];
    const float* enc_n2_b  = (const float*)d_in[15];
    const float* gcn_w1    = (const float*)d_in[16];
    const float* gcn_b1    = (const float*)d_in[17];
    const float* gcn_w2    = (const float*)d_in[18];
    const float* gcn_b2    = (const float*)d_in[19];
    const float* ca1_qkv_w = (const float*)d_in[20];
    const float* ca1_qkv_b = (const float*)d_in[21];
    const float* ca1_out_w = (const float*)d_in[22];
    const float* ca1_out_b = (const float*)d_in[23];
    const float* ca1_n_g   = (const float*)d_in[24];
    const float* ca1_n_b   = (const float*)d_in[25];
    const float* ca2_qkv_w = (const float*)d_in[26];
    const float* ca2_qkv_b = (const float*)d_in[27];
    const float* ca2_out_w = (const float*)d_in[28];
    const float* ca2_out_b = (const float*)d_in[29];
    const float* ca2_n_g   = (const float*)d_in[30];
    const float* ca2_n_b   = (const float*)d_in[31];
    const float* cls_w1    = (const float*)d_in[32];
    const float* cls_b1    = (const float*)d_in[33];
    const float* cls_w2    = (const float*)d_in[34];
    const float* cls_b2    = (const float*)d_in[35];

    char* wsb = (char*)d_ws;
    size_t off = 0;
    auto alloc = [&](size_t bytes) { char* r = wsb + off; off += (bytes + 255) & ~(size_t)255; return r; };
    short* bufBig = (short*)alloc((size_t)MR * 1024 * 2);          // 128 planes x MR
    short* fcb    = (short*)alloc((size_t)56 * MR * 8 * 2);        // P8 K448
    short* anT    = (short*)alloc((size_t)NB * 56 * 512 * 8 * 2);
    short* bufH   = (short*)alloc((size_t)32 * MR * 8 * 2);
    short* bufA   = (short*)alloc((size_t)32 * MR * 8 * 2);
    short* bufB   = (short*)alloc((size_t)32 * MR * 8 * 2);
    short* bufC   = (short*)alloc((size_t)32 * MR * 8 * 2);
    short* bufZS  = (short*)alloc((size_t)32 * MR * 8 * 2);
    short* Zr     = (short*)alloc((size_t)NB * 102400 * 2);
    short* projwb = (short*)alloc((size_t)56 * 256 * 8 * 2);
    short* qkvwb  = (short*)alloc((size_t)32 * 1536 * 8 * 2);
    short* outwb  = (short*)alloc((size_t)32 * 512 * 8 * 2);
    short* l1wb   = (short*)alloc((size_t)32 * 2048 * 8 * 2);
    short* l2wb   = (short*)alloc((size_t)128 * 512 * 8 * 2);
    short* gw1b   = (short*)alloc((size_t)56 * 256 * 8 * 2);
    short* gw2b   = (short*)alloc((size_t)32 * 256 * 8 * 2);
    short* c1qb   = (short*)alloc((size_t)32 * 768 * 8 * 2);
    short* c1ob   = (short*)alloc((size_t)32 * 256 * 8 * 2);
    short* c2qb   = (short*)alloc((size_t)32 * 768 * 8 * 2);
    short* c2ob   = (short*)alloc((size_t)32 * 256 * 8 * 2);
    float* dinv   = (float*)alloc((size_t)MR * 4);
    float* clsh   = (float*)alloc((size_t)NB * 128 * 4);
    // GCN temporaries aliased into bufBig (dead between encoder and CA phases)
    short* scb = bufBig;                                   // [64][56][512][8]
    short* XT1 = bufBig + (size_t)64 * 56 * 512 * 8;       // [64][56][256][8]
    short* h1  = bufBig;                                   // [64][32][512][8]
    short* XT2 = XT1;

    dim3 blk(256);
    auto cgrid = [](long long n) { return dim3((unsigned)((n + 255) / 256)); };

    // ---- conversions to P8 ----
    conv_p8<<<cgrid((long long)MR * 448), blk, 0, stream>>>(fc, fcb, MR, 400, 448, MR);
    conv_p8<<<cgrid(256 * 448), blk, 0, stream>>>(proj_w, projwb, 256, 400, 448, 256);
    conv_p8<<<cgrid(1536 * 256), blk, 0, stream>>>(enc_qkv_w, qkvwb, 1536, 256, 256, 1536);
    conv_p8<<<cgrid(512 * 256), blk, 0, stream>>>(enc_out_w, outwb, 512, 256, 256, 512);
    conv_p8<<<cgrid(2048 * 256), blk, 0, stream>>>(enc_l1_w, l1wb, 2048, 256, 256, 2048);
    conv_p8<<<cgrid(512 * 1024), blk, 0, stream>>>(enc_l2_w, l2wb, 512, 1024, 1024, 512);
    conv_p8<<<cgrid(256 * 448), blk, 0, stream>>>(gcn_w1, gw1b, 256, 400, 448, 256);
    conv_p8<<<cgrid(256 * 256), blk, 0, stream>>>(gcn_w2, gw2b, 256, 256, 256, 256);
    conv_p8<<<cgrid(768 * 256), blk, 0, stream>>>(ca1_qkv_w, c1qb, 768, 256, 256, 768);
    conv_p8<<<cgrid(256 * 256), blk, 0, stream>>>(ca1_out_w, c1ob, 256, 256, 256, 256);
    conv_p8<<<cgrid(768 * 256), blk, 0, stream>>>(ca2_qkv_w, c2qb, 768, 256, 256, 768);
    conv_p8<<<cgrid(256 * 256), blk, 0, stream>>>(ca2_out_w, c2ob, 256, 256, 256, 256);

    // ---- FC branch ----
    gemm_p8<<<dim3(2, 200, 1), blk, 0, stream>>>(
        fcb, MR, 0, projwb, 256, 0, proj_b, bufH, MR, 0, 0, MR, 256, 256, 448, 0);
    for (int l = 0; l < 2; ++l) {
        gemm_p8<<<dim3(6, 200, 1), blk, 0, stream>>>(
            bufH, MR, 0, qkvwb + (size_t)l * 768 * 8, 1536, 0, enc_qkv_b + l * 768,
            bufBig, MR, 0, 0, MR, 768, 768, 256, 0);
        attn_p8<<<dim3(7, NHH, NB), blk, 0, stream>>>(bufBig, bufA);
        gemm_p8<<<dim3(2, 200, 1), blk, 0, stream>>>(
            bufA, MR, 0, outwb + (size_t)l * 256 * 8, 512, 0, enc_out_b + l * 256,
            bufB, MR, 0, 0, MR, 256, 256, 256, 0);
        ln_res_p8<<<400, blk, 0, stream>>>(bufH, bufB, enc_n1_g + l * DD, enc_n1_b + l * DD, bufH);
        gemm_p8<<<dim3(8, 200, 1), blk, 0, stream>>>(
            bufH, MR, 0, l1wb + (size_t)l * 1024 * 8, 2048, 0, enc_l1_b + l * 1024,
            bufBig, MR, 0, 0, MR, 1024, 1024, 256, 1);
        gemm_p8<<<dim3(2, 200, 1), blk, 0, stream>>>(
            bufBig, MR, 0, l2wb + (size_t)l * 256 * 8, 512, 0, enc_l2_b + l * 256,
            bufA, MR, 0, 0, MR, 256, 256, 1024, 0);
        ln_res_p8<<<400, blk, 0, stream>>>(bufH, bufA, enc_n2_g + l * DD, enc_n2_b + l * DD, bufH);
    }

    // ---- GCN branch ----
    colsum_dinv<<<dim3(2, NB), blk, 0, stream>>>(sc, dinv);
    sc_prep<<<dim3(7, 7, NB), blk, 0, stream>>>(sc, dinv, scb, anT);
    gemm_p8<<<dim3(4, 2, NB), blk, 0, stream>>>(
        gw1b, 256, 0, scb, 512, 56LL * 512 * 8, nullptr,
        XT1, 256, 0, 56LL * 256 * 8, 256, 400, 448, 448, 0);
    gemm_p8<<<dim3(2, 4, NB), blk, 0, stream>>>(
        anT, 512, 56LL * 512 * 8, XT1, 256, 56LL * 256 * 8, gcn_b1,
        h1, 512, 0, 32LL * 512 * 8, 400, 256, 256, 448, 1);
    gemm_p8<<<dim3(4, 2, NB), blk, 0, stream>>>(
        gw2b, 256, 0, h1, 512, 32LL * 512 * 8, nullptr,
        XT2, 256, 0, 56LL * 256 * 8, 256, 400, 448, 256, 0);
    gemm_p8<<<dim3(2, 4, NB), blk, 0, stream>>>(
        anT, 512, 56LL * 512 * 8, XT2, 256, 56LL * 256 * 8, gcn_b2,
        bufZS, MR, 400, 0, 400, 256, 256, 448, 0);

    // ---- Cross attention 1: Q = Z_F, KV = Z_S ----
    gemm_p8<<<dim3(2, 200, 1), blk, 0, stream>>>(
        bufH, MR, 0, c1qb, 768, 0, ca1_qkv_b, bufBig, MR, 0, 0, MR, 256, 256, 256, 0);
    gemm_p8<<<dim3(4, 200, 1), blk, 0, stream>>>(
        bufZS, MR, 0, c1qb + 256 * 8, 768, 0, ca1_qkv_b + 256,
        bufBig + (size_t)32 * MR * 8, MR, 0, 0, MR, 512, 512, 256, 0);
    attn_p8<<<dim3(7, NHH, NB), blk, 0, stream>>>(bufBig, bufA);
    gemm_p8<<<dim3(2, 200, 1), blk, 0, stream>>>(
        bufA, MR, 0, c1ob, 256, 0, ca1_out_b, bufB, MR, 0, 0, MR, 256, 256, 256, 0);
    ln_res_p8<<<400, blk, 0, stream>>>(bufH, bufB, ca1_n_g, ca1_n_b, bufC);

    // ---- Cross attention 2: Q = Z_S, KV = Z_F ----
    gemm_p8<<<dim3(2, 200, 1), blk, 0, stream>>>(
        bufZS, MR, 0, c2qb, 768, 0, ca2_qkv_b, bufBig, MR, 0, 0, MR, 256, 256, 256, 0);
    gemm_p8<<<dim3(4, 200, 1), blk, 0, stream>>>(
        bufH, MR, 0, c2qb + 256 * 8, 768, 0, ca2_qkv_b + 256,
        bufBig + (size_t)32 * MR * 8, MR, 0, 0, MR, 512, 512, 256, 0);
    attn_p8<<<dim3(7, NHH, NB), blk, 0, stream>>>(bufBig, bufA);
    gemm_p8<<<dim3(2, 200, 1), blk, 0, stream>>>(
        bufA, MR, 0, c2ob, 256, 0, ca2_out_b, bufB, MR, 0, 0, MR, 256, 256, 256, 0);
    ln_res_p8<<<400, blk, 0, stream>>>(bufZS, bufB, ca2_n_g, ca2_n_b, bufZS);

    // ---- Classifier ----
    zjoint_pack<<<dim3(100, 32), blk, 0, stream>>>(bufC, bufZS, Zr);
    zero_buf<<<cgrid(NB * 128), blk, 0, stream>>>(clsh, NB * 128);
    cls_splitk<<<dim3(2, 100), blk, 0, stream>>>(Zr, cls_w1, clsh);
    logits_final<<<NB, 128, 0, stream>>>(clsh, cls_b1, cls_w2, cls_b2, (float*)d_out);
}

// Round 6
// 1306.105 us; speedup vs baseline: 1.1234x; 1.0510x over previous
//
#include <hip/hip_runtime.h>
#include <math.h>

// Problem constants
#define NB   64
#define NN   400
#define DD   256
#define NHH  4
#define HDD  64
#define MR   25600            // NB*NN

typedef __attribute__((ext_vector_type(8))) short bf16x8;
typedef __attribute__((ext_vector_type(4))) float f32x4;

__device__ __forceinline__ short f2bf(float x) {
    union { float f; unsigned u; } v; v.f = x;
    return (short)((v.u + 0x7FFFu + ((v.u >> 16) & 1u)) >> 16);
}
__device__ __forceinline__ float bf2f(short s) {
    union { unsigned u; float f; } v; v.u = ((unsigned)(unsigned short)s) << 16;
    return v.f;
}
// async global->LDS, 16 B/lane; src = per-lane addr, LDS dest = wave-uniform base
__device__ __forceinline__ void gl_lds16(const void* g, void* l) {
    __builtin_amdgcn_global_load_lds(
        (const __attribute__((address_space(1))) unsigned*)g,
        (__attribute__((address_space(3))) unsigned*)l, 16, 0, 0);
}

// ---------------------------------------------------------------------------
// P8 layout: element (row, k) lives at ((k>>3)*rows + row)*8 + (k&7) (bf16).
// = the 16x16x32 MFMA fragment layout; staging is contiguous 1 KiB bursts.
// ---------------------------------------------------------------------------

// bf16 GEMM, 128x128 tile, BK=64, double-buffered LDS prefetch. (unchanged r5)
__global__ __launch_bounds__(256) void gemm_p8(
    const short* __restrict__ A, int arows, long long sA,
    const short* __restrict__ B, int brows, long long sB,
    const float* __restrict__ bias,
    short* __restrict__ C, int crows, int crz, long long sCe,
    int M, int N, int Npad, int K, int relu)
{
    __shared__ short Al[2][8 * 128 * 8];
    __shared__ short Bl[2][8 * 128 * 8];
    const int tid = threadIdx.x;
    const int z = blockIdx.z;
    const int m0 = blockIdx.y * 128, n0 = blockIdx.x * 128;
    const short* Ab = A + (size_t)z * sA;
    const short* Bb = B + (size_t)z * sB;

    const int w = tid >> 6, lane = tid & 63;
    const int quad = lane >> 4, l15 = lane & 15;
    const int wm = w & 1, wn = w >> 1;

    f32x4 acc[4][4] = {};

    const int KT = K >> 6;
    auto stage = [&](int buf, int kt) {
        const int gp0 = kt << 3;
#pragma unroll
        for (int pp = 0; pp < 2; ++pp) {
            const int p = w + pp * 4;
            gl_lds16(Ab + ((size_t)(gp0 + p) * arows + m0 + lane) * 8,      &Al[buf][(p * 128) * 8]);
            gl_lds16(Ab + ((size_t)(gp0 + p) * arows + m0 + 64 + lane) * 8, &Al[buf][(p * 128 + 64) * 8]);
            gl_lds16(Bb + ((size_t)(gp0 + p) * brows + n0 + lane) * 8,      &Bl[buf][(p * 128) * 8]);
            gl_lds16(Bb + ((size_t)(gp0 + p) * brows + n0 + 64 + lane) * 8, &Bl[buf][(p * 128 + 64) * 8]);
        }
    };
    stage(0, 0);
    __syncthreads();
    for (int kt = 0; kt < KT; ++kt) {
        const int cur = kt & 1;
        if (kt + 1 < KT) stage(cur ^ 1, kt + 1);
#pragma unroll
        for (int kb = 0; kb < 2; ++kb) {
            bf16x8 af[4], bfr[4];
#pragma unroll
            for (int mi = 0; mi < 4; ++mi)
                af[mi] = *reinterpret_cast<const bf16x8*>(
                    &Al[cur][((kb * 4 + quad) * 128 + wm * 64 + mi * 16 + l15) * 8]);
#pragma unroll
            for (int ni = 0; ni < 4; ++ni)
                bfr[ni] = *reinterpret_cast<const bf16x8*>(
                    &Bl[cur][((kb * 4 + quad) * 128 + wn * 64 + ni * 16 + l15) * 8]);
#pragma unroll
            for (int mi = 0; mi < 4; ++mi)
#pragma unroll
                for (int ni = 0; ni < 4; ++ni)
                    acc[mi][ni] = __builtin_amdgcn_mfma_f32_16x16x32_bf16(af[mi], bfr[ni], acc[mi][ni], 0, 0, 0);
        }
        __syncthreads();
    }

    short* Cbz = C + (size_t)z * sCe;
    const long long zr = (long long)z * crz;
#pragma unroll
    for (int mi = 0; mi < 4; ++mi) {
#pragma unroll
        for (int r = 0; r < 4; ++r) {
            int row = m0 + wm * 64 + mi * 16 + quad * 4 + r;
            if (row >= M) continue;
#pragma unroll
            for (int ni = 0; ni < 4; ++ni) {
                int col = n0 + wn * 64 + ni * 16 + l15;
                if (col >= Npad) continue;
                float v = 0.0f;
                if (col < N) {
                    v = acc[mi][ni][r];
                    if (bias) v += bias[col];
                    if (relu) v = fmaxf(v, 0.0f);
                }
                Cbz[((size_t)(col >> 3) * crows + zr + row) * 8 + (col & 7)] = f2bf(v);
            }
        }
    }
}

// ---------------------------------------------------------------------------
// V transpose: per (b,h), vT[(bh*56 + kp)*64 + d]*8 + (key&7) = V[key][d],
// keys >= 400 zeroed. Read side coalesced; LDS 64x66 transpose (conflict-free).
// ---------------------------------------------------------------------------
__global__ __launch_bounds__(256) void vtrans(
    const short* __restrict__ qkv, short* __restrict__ vT)
{
    __shared__ short tile[64][66];
    const int c = blockIdx.x, h = blockIdx.y, b = blockIdx.z;
    const int tid = threadIdx.x;
    const size_t bh = (size_t)b * NHH + h;
    for (int t = tid; t < 512; t += 256) {
        int pp = t >> 6, l = t & 63;
        int j = c * 64 + l;
        bf16x8 v;
        if (j < NN)
            v = *reinterpret_cast<const bf16x8*>(
                qkv + (((size_t)(64 + 8 * h + pp)) * MR + (size_t)b * NN + j) * 8);
        else { for (int e = 0; e < 8; ++e) v[e] = 0; }
#pragma unroll
        for (int e = 0; e < 8; ++e) tile[l][pp * 8 + e] = v[e];
    }
    __syncthreads();
    for (int t = tid; t < 512; t += 256) {
        int kq = t >> 6, d = t & 63;
        int kp = c * 8 + kq;             // < 56 always
        bf16x8 o;
#pragma unroll
        for (int e = 0; e < 8; ++e) o[e] = tile[kq * 8 + e][d];
        *reinterpret_cast<bf16x8*>(vT + ((bh * 56 + kp) * 64 + d) * 8) = o;
    }
}

// ---------------------------------------------------------------------------
// Attention over P8 QKV buffer (96 planes x MR rows): Q planes 8h.., K 32+8h..,
// V via pre-transposed vT. Out -> P8 (32 planes x MR).
// ---------------------------------------------------------------------------
__global__ __launch_bounds__(256) void attn_p8(
    const short* __restrict__ qkv, const short* __restrict__ vT,
    short* __restrict__ Out)
{
    __shared__ short KP[8 * 448 * 8];   // K [8][448][8]; later P [52][64][8]
    __shared__ short QV[8 * 64 * 8];    // Q [8][64][8]; later V chunks [8][64][8]
    const int qt = blockIdx.x, h = blockIdx.y, b = blockIdx.z;
    const int tid = threadIdx.x;
    const int w = tid >> 6, lane = tid & 63;
    const int quad = lane >> 4, l15 = lane & 15;
    const size_t rowb = (size_t)b * NN;
    const size_t bh = (size_t)b * NHH + h;

    for (int j = w; j < 8; j += 4)
        gl_lds16(qkv + (((size_t)(8 * h + j)) * MR + rowb + qt * 64 + lane) * 8, &QV[(j * 64) * 8]);
    for (int t = w; t < 56; t += 4) {
        int j = t / 7, c = t - j * 7;
        gl_lds16(qkv + (((size_t)(32 + 8 * h + j)) * MR + rowb + c * 64 + lane) * 8,
                 &KP[(j * 448 + c * 64) * 8]);
    }
    __syncthreads();

    bf16x8 aq0 = *reinterpret_cast<const bf16x8*>(&QV[(quad * 64 + w * 16 + l15) * 8]);
    bf16x8 aq1 = *reinterpret_cast<const bf16x8*>(&QV[((4 + quad) * 64 + w * 16 + l15) * 8]);
    f32x4 sacc[25];
#pragma unroll
    for (int nt = 0; nt < 25; ++nt) { sacc[nt][0] = 0; sacc[nt][1] = 0; sacc[nt][2] = 0; sacc[nt][3] = 0; }
#pragma unroll
    for (int nt = 0; nt < 25; ++nt) {
        bf16x8 b0 = *reinterpret_cast<const bf16x8*>(&KP[(quad * 448 + nt * 16 + l15) * 8]);
        bf16x8 b1 = *reinterpret_cast<const bf16x8*>(&KP[((4 + quad) * 448 + nt * 16 + l15) * 8]);
        sacc[nt] = __builtin_amdgcn_mfma_f32_16x16x32_bf16(aq0, b0, sacc[nt], 0, 0, 0);
        sacc[nt] = __builtin_amdgcn_mfma_f32_16x16x32_bf16(aq1, b1, sacc[nt], 0, 0, 0);
    }

    float mx[4] = {-3e38f, -3e38f, -3e38f, -3e38f}, sm[4] = {0, 0, 0, 0};
#pragma unroll
    for (int nt = 0; nt < 25; ++nt)
#pragma unroll
        for (int r = 0; r < 4; ++r) mx[r] = fmaxf(mx[r], sacc[nt][r]);
#pragma unroll
    for (int r = 0; r < 4; ++r) {
        mx[r] = fmaxf(mx[r], __shfl_xor(mx[r], 1));
        mx[r] = fmaxf(mx[r], __shfl_xor(mx[r], 2));
        mx[r] = fmaxf(mx[r], __shfl_xor(mx[r], 4));
        mx[r] = fmaxf(mx[r], __shfl_xor(mx[r], 8));
    }
#pragma unroll
    for (int nt = 0; nt < 25; ++nt)
#pragma unroll
        for (int r = 0; r < 4; ++r) {
            float e = __expf((sacc[nt][r] - mx[r]) * 0.125f);
            sacc[nt][r] = e;
            sm[r] += e;
        }
#pragma unroll
    for (int r = 0; r < 4; ++r) {
        sm[r] += __shfl_xor(sm[r], 1);
        sm[r] += __shfl_xor(sm[r], 2);
        sm[r] += __shfl_xor(sm[r], 4);
        sm[r] += __shfl_xor(sm[r], 8);
    }
    __syncthreads();

#pragma unroll
    for (int nt = 0; nt < 25; ++nt)
#pragma unroll
        for (int r = 0; r < 4; ++r) {
            int colk = nt * 16 + l15;
            KP[((colk >> 3) * 64 + w * 16 + quad * 4 + r) * 8 + (colk & 7)] = f2bf(sacc[nt][r]);
        }
    for (int idx = tid; idx < 1024; idx += 256) KP[25600 + idx] = 0;

    f32x4 oacc[4];
#pragma unroll
    for (int dt = 0; dt < 4; ++dt) { oacc[dt][0] = 0; oacc[dt][1] = 0; oacc[dt][2] = 0; oacc[dt][3] = 0; }
    for (int kt = 0; kt < 13; ++kt) {
        if ((kt & 1) == 0) {
            __syncthreads();
            const int cp = (kt >> 1) * 8;
            gl_lds16(vT + ((bh * 56 + cp + w) * 64 + lane) * 8,     &QV[(w * 64) * 8]);
            gl_lds16(vT + ((bh * 56 + cp + 4 + w) * 64 + lane) * 8, &QV[((4 + w) * 64) * 8]);
            __syncthreads();
        }
        bf16x8 pa = *reinterpret_cast<const bf16x8*>(&KP[((kt * 4 + quad) * 64 + w * 16 + l15) * 8]);
#pragma unroll
        for (int dt = 0; dt < 4; ++dt) {
            bf16x8 vb = *reinterpret_cast<const bf16x8*>(&QV[(((kt & 1) * 4 + quad) * 64 + dt * 16 + l15) * 8]);
            oacc[dt] = __builtin_amdgcn_mfma_f32_16x16x32_bf16(pa, vb, oacc[dt], 0, 0, 0);
        }
    }
#pragma unroll
    for (int r = 0; r < 4; ++r) {
        int row = qt * 64 + w * 16 + quad * 4 + r;
        if (row >= NN) continue;
        float inv = 1.0f / sm[r];
#pragma unroll
        for (int dt = 0; dt < 4; ++dt) {
            int col = dt * 16 + l15;
            Out[(((size_t)(8 * h + (col >> 3))) * MR + rowb + row) * 8 + (col & 7)] =
                f2bf(oacc[dt][r] * inv);
        }
    }
}

// ---------------------------------------------------------------------------
// fp32 [R x K] row-major -> P8 bf16 with K zero-padded to Kp, plane rows PR
// ---------------------------------------------------------------------------
__global__ void conv_p8(const float* __restrict__ src, short* __restrict__ dst,
                        int R, int K, int Kp, int PR)
{
    long long idx = (long long)blockIdx.x * 256 + threadIdx.x;
    if (idx >= (long long)R * Kp) return;
    int r = (int)(idx / Kp), k = (int)(idx - (long long)r * Kp);
    dst[((size_t)(k >> 3) * PR + r) * 8 + (k & 7)] = (k < K) ? f2bf(src[(size_t)r * K + k]) : (short)0;
}

// ---------------------------------------------------------------------------
// cls_w1 [128][102400] fp32 -> P8 bf16 (PR=128) via LDS transpose, coalesced.
// grid = 800 blocks, block handles k-chunk of 128.
// ---------------------------------------------------------------------------
__global__ __launch_bounds__(256) void w1_p8(
    const float* __restrict__ W1, short* __restrict__ Wp)
{
    __shared__ float tile[128][129];
    const int k0 = blockIdx.x * 128;
    const int tid = threadIdx.x;
    for (int t = 0; t < 16; ++t) {
        int idx = t * 256 + tid;               // 4096 float4 slots
        int r = idx >> 5, k4 = idx & 31;
        float4 v = *(const float4*)(W1 + (size_t)r * 102400 + k0 + k4 * 4);
        tile[r][k4 * 4 + 0] = v.x; tile[r][k4 * 4 + 1] = v.y;
        tile[r][k4 * 4 + 2] = v.z; tile[r][k4 * 4 + 3] = v.w;
    }
    __syncthreads();
    for (int t = 0; t < 8; ++t) {
        int idx = t * 256 + tid;               // 2048 (plane,row) slots
        int pidx = idx >> 7, r = idx & 127;
        bf16x8 o;
#pragma unroll
        for (int e = 0; e < 8; ++e) o[e] = f2bf(tile[r][pidx * 8 + e]);
        *reinterpret_cast<bf16x8*>(Wp + (((size_t)(k0 >> 3) + pidx) * 128 + r) * 8) = o;
    }
}

// ---------------------------------------------------------------------------
__global__ void colsum_dinv(const float* __restrict__ sc, float* __restrict__ dinv)
{
    int b = blockIdx.y;
    int j = blockIdx.x * 256 + threadIdx.x;
    if (j >= NN) return;
    const float* p = sc + (size_t)b * NN * NN + j;
    float s = 0.0f;
    for (int i = 0; i < NN; ++i) s += p[(size_t)i * NN];
    dinv[b * NN + j] = (s > 0.0f) ? 1.0f / sqrtf(s) : 0.0f;
}

// ---------------------------------------------------------------------------
__global__ __launch_bounds__(256) void sc_prep(
    const float* __restrict__ sc, const float* __restrict__ dinv,
    short* __restrict__ scb, short* __restrict__ anT)
{
    __shared__ float tile[64][65];
    const int b = blockIdx.z;
    const int i0 = blockIdx.y * 64, j0 = blockIdx.x * 64;
    const int tid = threadIdx.x;
    const float* sb = sc + (size_t)b * NN * NN;
    short* scbb = scb + (size_t)b * 56 * 512 * 8;
    short* anTb = anT + (size_t)b * 56 * 512 * 8;
    for (int e = tid; e < 4096; e += 256) {
        int r = e >> 6, c = e & 63;
        int i = i0 + r, j = j0 + c;
        tile[r][c] = (i < NN && j < NN) ? sb[(size_t)i * NN + j] : 0.0f;
    }
    __syncthreads();
    for (int e = tid; e < 4096; e += 256) {
        int r = e >> 6, c = e & 63;
        int i = i0 + r, j = j0 + c;
        scbb[((size_t)(j >> 3) * 512 + i) * 8 + (j & 7)] = f2bf(tile[r][c]);
        float v = 0.0f;
        if (i < NN && j < NN) v = tile[r][c] * dinv[b * NN + i] * dinv[b * NN + j];
        anTb[((size_t)(i >> 3) * 512 + j) * 8 + (i & 7)] = f2bf(v);
    }
}

// ---------------------------------------------------------------------------
// Fused residual + LayerNorm over P8. Block = 64 rows x 4 plane-quarters.
// ---------------------------------------------------------------------------
__global__ __launch_bounds__(256) void ln_res_p8(
    const short* __restrict__ x, const short* __restrict__ a,
    const float* __restrict__ g, const float* __restrict__ bb,
    short* __restrict__ y)
{
    __shared__ float gs[256], bs[256];
    __shared__ float red[2][4][64];
    const int tid = threadIdx.x;
    gs[tid] = g[tid]; bs[tid] = bb[tid];
    const int rl = tid & 63;
    const int part = tid >> 6;
    const int row = blockIdx.x * 64 + rl;
    float sum = 0.0f, sq = 0.0f;
    float vv[8][8];
#pragma unroll
    for (int i = 0; i < 8; ++i) {
        int p = part * 8 + i;
        bf16x8 xv = *reinterpret_cast<const bf16x8*>(x + ((size_t)p * MR + row) * 8);
        bf16x8 av = *reinterpret_cast<const bf16x8*>(a + ((size_t)p * MR + row) * 8);
#pragma unroll
        for (int e = 0; e < 8; ++e) {
            float v = bf2f(xv[e]) + bf2f(av[e]);
            vv[i][e] = v;
            sum += v; sq += v * v;
        }
    }
    red[0][part][rl] = sum; red[1][part][rl] = sq;
    __syncthreads();
    sum = red[0][0][rl] + red[0][1][rl] + red[0][2][rl] + red[0][3][rl];
    sq  = red[1][0][rl] + red[1][1][rl] + red[1][2][rl] + red[1][3][rl];
    float mu = sum * (1.0f / 256.0f);
    float var = sq * (1.0f / 256.0f) - mu * mu;
    float rstd = 1.0f / sqrtf(fmaxf(var, 0.0f) + 1e-5f);
#pragma unroll
    for (int i = 0; i < 8; ++i) {
        int p = part * 8 + i;
        bf16x8 o;
#pragma unroll
        for (int e = 0; e < 8; ++e)
            o[e] = f2bf((vv[i][e] - mu) * rstd * gs[p * 8 + e] + bs[p * 8 + e]);
        *reinterpret_cast<bf16x8*>(y + ((size_t)p * MR + row) * 8) = o;
    }
}

// ---------------------------------------------------------------------------
// Classifier MFMA split-K: block j (0..399) computes the 64x128 contribution
// of feature block j (k = j*256 + d). A = 0.5*(C1+C2) read from P8 directly;
// W from w1_p8 (P8, PR=128). Partials [400][64][128] -> cls_reduce.
// ---------------------------------------------------------------------------
__global__ __launch_bounds__(256) void cls_gemm(
    const short* __restrict__ C1, const short* __restrict__ C2,
    const short* __restrict__ Wp, float* __restrict__ partial)
{
    __shared__ short Al[32 * 64 * 8];    // [32 planes][64 b][8]
    __shared__ short Wl[8 * 128 * 8];    // [8 planes][128 n][8]
    const int j = blockIdx.x;
    const int tid = threadIdx.x;
    const int w = tid >> 6, lane = tid & 63;
    const int quad = lane >> 4, l15 = lane & 15;

    // stage A: 32 planes x 64 batch rows (scattered 16B reads, once per block)
    for (int s = 0; s < 8; ++s) {
        int idx = s * 256 + tid;
        int p = idx >> 6, b = idx & 63;
        size_t ad = ((size_t)p * MR + (size_t)b * NN + j) * 8;
        bf16x8 a = *reinterpret_cast<const bf16x8*>(C1 + ad);
        bf16x8 c = *reinterpret_cast<const bf16x8*>(C2 + ad);
        bf16x8 o;
#pragma unroll
        for (int e = 0; e < 8; ++e) o[e] = f2bf(0.5f * (bf2f(a[e]) + bf2f(c[e])));
        *reinterpret_cast<bf16x8*>(&Al[(p * 64 + b) * 8]) = o;
    }

    f32x4 acc[4][2] = {};
    const size_t wp0 = (size_t)j * 32;
    for (int s = 0; s < 4; ++s) {
        // stage W planes j*32 + s*8 + [0..8): wave w loads rel planes w, w+4
#pragma unroll
        for (int pp = 0; pp < 2; ++pp) {
            int p = w + pp * 4;
            gl_lds16(Wp + ((wp0 + s * 8 + p) * 128 + lane) * 8,      &Wl[(p * 128) * 8]);
            gl_lds16(Wp + ((wp0 + s * 8 + p) * 128 + 64 + lane) * 8, &Wl[(p * 128 + 64) * 8]);
        }
        __syncthreads();
#pragma unroll
        for (int kb = 0; kb < 2; ++kb) {
            bf16x8 af[4], bfr[2];
#pragma unroll
            for (int mi = 0; mi < 4; ++mi)
                af[mi] = *reinterpret_cast<const bf16x8*>(
                    &Al[((s * 8 + kb * 4 + quad) * 64 + mi * 16 + l15) * 8]);
#pragma unroll
            for (int ni = 0; ni < 2; ++ni)
                bfr[ni] = *reinterpret_cast<const bf16x8*>(
                    &Wl[((kb * 4 + quad) * 128 + w * 32 + ni * 16 + l15) * 8]);
#pragma unroll
            for (int mi = 0; mi < 4; ++mi)
#pragma unroll
                for (int ni = 0; ni < 2; ++ni)
                    acc[mi][ni] = __builtin_amdgcn_mfma_f32_16x16x32_bf16(af[mi], bfr[ni], acc[mi][ni], 0, 0, 0);
        }
        __syncthreads();
    }
    float* pj = partial + (size_t)j * 8192;
#pragma unroll
    for (int mi = 0; mi < 4; ++mi)
#pragma unroll
        for (int r = 0; r < 4; ++r) {
            int row = mi * 16 + quad * 4 + r;
#pragma unroll
            for (int ni = 0; ni < 2; ++ni)
                pj[row * 128 + w * 32 + ni * 16 + l15] = acc[mi][ni][r];
        }
}

__global__ void cls_reduce(const float* __restrict__ partial, float* __restrict__ clsh)
{
    int o = blockIdx.x * 256 + threadIdx.x;   // 8192
    float s = 0.0f;
    for (int kb = 0; kb < 400; ++kb) s += partial[(size_t)kb * 8192 + o];
    clsh[o] = s;
}

__global__ void logits_final(
    const float* __restrict__ clsh, const float* __restrict__ b1,
    const float* __restrict__ w2, const float* __restrict__ b2,
    float* __restrict__ out)
{
    __shared__ float t[128];
    int b = blockIdx.x;
    int tid = threadIdx.x;
    t[tid] = fmaxf(clsh[b * 128 + tid] + b1[tid], 0.0f);
    __syncthreads();
    if (tid < 2) {
        float s = b2[tid];
        for (int o = 0; o < 128; ++o) s += t[o] * w2[tid * 128 + o];
        out[b * 2 + tid] = s;
    }
}

// ---------------------------------------------------------------------------
extern "C" void kernel_launch(void* const* d_in, const int* in_sizes, int n_in,
                              void* d_out, int out_size, void* d_ws, size_t ws_size,
                              hipStream_t stream)
{
    const float* fc        = (const float*)d_in[0];
    const float* sc        = (const float*)d_in[1];
    const float* proj_w    = (const float*)d_in[2];
    const float* proj_b    = (const float*)d_in[3];
    const float* enc_qkv_w = (const float*)d_in[4];
    const float* enc_qkv_b = (const float*)d_in[5];
    const float* enc_out_w = (const float*)d_in[6];
    const float* enc_out_b = (const float*)d_in[7];
    const float* enc_l1_w  = (const float*)d_in[8];
    const float* enc_l1_b  = (const float*)d_in[9];
    const float* enc_l2_w  = (const float*)d_in[10];
    const float* enc_l2_b  = (const float*)d_in[11];
    const float* enc_n1_g  = (const float*)d_in[12];
    const float* enc_n1_b  = (const float*)d_in[13];
    const float* enc_n2_g  = (const float*)d_in[14];
    const float* enc_n2_b  = (const float*)d_in[15];
    const float* gcn_w1    = (const float*)d_in[16];
    const float* gcn_b1    = (const float*)d_in[17];
    const float* gcn_w2    = (const float*)d_in[18];
    const float* gcn_b2    = (const float*)d_in[19];
    const float* ca1_qkv_w = (const float*)d_in[20];
    const float* ca1_qkv_b = (const float*)d_in[21];
    const float* ca1_out_w = (const float*)d_in[22];
    const float* ca1_out_b = (const float*)d_in[23];
    const float* ca1_n_g   = (const float*)d_in[24];
    const float* ca1_n_b   = (const float*)d_in[25];
    const float* ca2_qkv_w = (const float*)d_in[26];
    const float* ca2_qkv_b = (const float*)d_in[27];
    const float* ca2_out_w = (const float*)d_in[28];
    const float* ca2_out_b = (const float*)d_in[29];
    const float* ca2_n_g   = (const float*)d_in[30];
    const float* ca2_n_b   = (const float*)d_in[31];
    const float* cls_w1    = (const float*)d_in[32];
    const float* cls_b1    = (const float*)d_in[33];
    const float* cls_w2    = (const float*)d_in[34];
    const float* cls_b2    = (const float*)d_in[35];

    char* wsb = (char*)d_ws;
    size_t off = 0;
    auto alloc = [&](size_t bytes) { char* r = wsb + off; off += (bytes + 255) & ~(size_t)255; return r; };
    short* bufBig = (short*)alloc((size_t)MR * 1024 * 2);          // 128 planes x MR
    short* fcb    = (short*)alloc((size_t)56 * MR * 8 * 2);        // P8 K448
    short* anT    = (short*)alloc((size_t)NB * 56 * 512 * 8 * 2);
    short* bufH   = (short*)alloc((size_t)32 * MR * 8 * 2);
    short* bufA   = (short*)alloc((size_t)32 * MR * 8 * 2);
    short* bufB   = (short*)alloc((size_t)32 * MR * 8 * 2);
    short* bufC   = (short*)alloc((size_t)32 * MR * 8 * 2);
    short* bufZS  = (short*)alloc((size_t)32 * MR * 8 * 2);
    short* vT     = (short*)alloc((size_t)NB * NHH * 56 * 64 * 8 * 2);
    short* w1b    = (short*)alloc((size_t)12800 * 128 * 8 * 2);    // 26 MB
    short* projwb = (short*)alloc((size_t)56 * 256 * 8 * 2);
    short* qkvwb  = (short*)alloc((size_t)32 * 1536 * 8 * 2);
    short* outwb  = (short*)alloc((size_t)32 * 512 * 8 * 2);
    short* l1wb   = (short*)alloc((size_t)32 * 2048 * 8 * 2);
    short* l2wb   = (short*)alloc((size_t)128 * 512 * 8 * 2);
    short* gw1b   = (short*)alloc((size_t)56 * 256 * 8 * 2);
    short* gw2b   = (short*)alloc((size_t)32 * 256 * 8 * 2);
    short* c1qb   = (short*)alloc((size_t)32 * 768 * 8 * 2);
    short* c1ob   = (short*)alloc((size_t)32 * 256 * 8 * 2);
    short* c2qb   = (short*)alloc((size_t)32 * 768 * 8 * 2);
    short* c2ob   = (short*)alloc((size_t)32 * 256 * 8 * 2);
    float* dinv   = (float*)alloc((size_t)MR * 4);
    float* clsh   = (float*)alloc((size_t)NB * 128 * 4);
    // aliases: GCN temps in bufBig (dead outside GCN); cls partials in fcb
    short* scb = bufBig;                                   // [64][56][512][8]
    short* XT1 = bufBig + (size_t)64 * 56 * 512 * 8;       // [64][56][256][8]
    short* h1  = bufBig;                                   // [64][32][512][8]
    short* XT2 = XT1;
    float* partial = (float*)fcb;                          // 400*8192*4 = 13 MB <= fcb

    dim3 blk(256);
    auto cgrid = [](long long n) { return dim3((unsigned)((n + 255) / 256)); };

    // ---- conversions to P8 ----
    conv_p8<<<cgrid((long long)MR * 448), blk, 0, stream>>>(fc, fcb, MR, 400, 448, MR);
    conv_p8<<<cgrid(256 * 448), blk, 0, stream>>>(proj_w, projwb, 256, 400, 448, 256);
    conv_p8<<<cgrid(1536 * 256), blk, 0, stream>>>(enc_qkv_w, qkvwb, 1536, 256, 256, 1536);
    conv_p8<<<cgrid(512 * 256), blk, 0, stream>>>(enc_out_w, outwb, 512, 256, 256, 512);
    conv_p8<<<cgrid(2048 * 256), blk, 0, stream>>>(enc_l1_w, l1wb, 2048, 256, 256, 2048);
    conv_p8<<<cgrid(512 * 1024), blk, 0, stream>>>(enc_l2_w, l2wb, 512, 1024, 1024, 512);
    conv_p8<<<cgrid(256 * 448), blk, 0, stream>>>(gcn_w1, gw1b, 256, 400, 448, 256);
    conv_p8<<<cgrid(256 * 256), blk, 0, stream>>>(gcn_w2, gw2b, 256, 256, 256, 256);
    conv_p8<<<cgrid(768 * 256), blk, 0, stream>>>(ca1_qkv_w, c1qb, 768, 256, 256, 768);
    conv_p8<<<cgrid(256 * 256), blk, 0, stream>>>(ca1_out_w, c1ob, 256, 256, 256, 256);
    conv_p8<<<cgrid(768 * 256), blk, 0, stream>>>(ca2_qkv_w, c2qb, 768, 256, 256, 768);
    conv_p8<<<cgrid(256 * 256), blk, 0, stream>>>(ca2_out_w, c2ob, 256, 256, 256, 256);
    w1_p8<<<800, blk, 0, stream>>>(cls_w1, w1b);

    // ---- FC branch ----
    gemm_p8<<<dim3(2, 200, 1), blk, 0, stream>>>(
        fcb, MR, 0, projwb, 256, 0, proj_b, bufH, MR, 0, 0, MR, 256, 256, 448, 0);
    for (int l = 0; l < 2; ++l) {
        gemm_p8<<<dim3(6, 200, 1), blk, 0, stream>>>(
            bufH, MR, 0, qkvwb + (size_t)l * 768 * 8, 1536, 0, enc_qkv_b + l * 768,
            bufBig, MR, 0, 0, MR, 768, 768, 256, 0);
        vtrans<<<dim3(7, NHH, NB), blk, 0, stream>>>(bufBig, vT);
        attn_p8<<<dim3(7, NHH, NB), blk, 0, stream>>>(bufBig, vT, bufA);
        gemm_p8<<<dim3(2, 200, 1), blk, 0, stream>>>(
            bufA, MR, 0, outwb + (size_t)l * 256 * 8, 512, 0, enc_out_b + l * 256,
            bufB, MR, 0, 0, MR, 256, 256, 256, 0);
        ln_res_p8<<<400, blk, 0, stream>>>(bufH, bufB, enc_n1_g + l * DD, enc_n1_b + l * DD, bufH);
        gemm_p8<<<dim3(8, 200, 1), blk, 0, stream>>>(
            bufH, MR, 0, l1wb + (size_t)l * 1024 * 8, 2048, 0, enc_l1_b + l * 1024,
            bufBig, MR, 0, 0, MR, 1024, 1024, 256, 1);
        gemm_p8<<<dim3(2, 200, 1), blk, 0, stream>>>(
            bufBig, MR, 0, l2wb + (size_t)l * 256 * 8, 512, 0, enc_l2_b + l * 256,
            bufA, MR, 0, 0, MR, 256, 256, 1024, 0);
        ln_res_p8<<<400, blk, 0, stream>>>(bufH, bufA, enc_n2_g + l * DD, enc_n2_b + l * DD, bufH);
    }

    // ---- GCN branch ----
    colsum_dinv<<<dim3(2, NB), blk, 0, stream>>>(sc, dinv);
    sc_prep<<<dim3(7, 7, NB), blk, 0, stream>>>(sc, dinv, scb, anT);
    gemm_p8<<<dim3(4, 2, NB), blk, 0, stream>>>(
        gw1b, 256, 0, scb, 512, 56LL * 512 * 8, nullptr,
        XT1, 256, 0, 56LL * 256 * 8, 256, 400, 448, 448, 0);
    gemm_p8<<<dim3(2, 4, NB), blk, 0, stream>>>(
        anT, 512, 56LL * 512 * 8, XT1, 256, 56LL * 256 * 8, gcn_b1,
        h1, 512, 0, 32LL * 512 * 8, 400, 256, 256, 448, 1);
    gemm_p8<<<dim3(4, 2, NB), blk, 0, stream>>>(
        gw2b, 256, 0, h1, 512, 32LL * 512 * 8, nullptr,
        XT2, 256, 0, 56LL * 256 * 8, 256, 400, 448, 256, 0);
    gemm_p8<<<dim3(2, 4, NB), blk, 0, stream>>>(
        anT, 512, 56LL * 512 * 8, XT2, 256, 56LL * 256 * 8, gcn_b2,
        bufZS, MR, 400, 0, 400, 256, 256, 448, 0);

    // ---- Cross attention 1: Q = Z_F, KV = Z_S ----
    gemm_p8<<<dim3(2, 200, 1), blk, 0, stream>>>(
        bufH, MR, 0, c1qb, 768, 0, ca1_qkv_b, bufBig, MR, 0, 0, MR, 256, 256, 256, 0);
    gemm_p8<<<dim3(4, 200, 1), blk, 0, stream>>>(
        bufZS, MR, 0, c1qb + 256 * 8, 768, 0, ca1_qkv_b + 256,
        bufBig + (size_t)32 * MR * 8, MR, 0, 0, MR, 512, 512, 256, 0);
    vtrans<<<dim3(7, NHH, NB), blk, 0, stream>>>(bufBig, vT);
    attn_p8<<<dim3(7, NHH, NB), blk, 0, stream>>>(bufBig, vT, bufA);
    gemm_p8<<<dim3(2, 200, 1), blk, 0, stream>>>(
        bufA, MR, 0, c1ob, 256, 0, ca1_out_b, bufB, MR, 0, 0, MR, 256, 256, 256, 0);
    ln_res_p8<<<400, blk, 0, stream>>>(bufH, bufB, ca1_n_g, ca1_n_b, bufC);

    // ---- Cross attention 2: Q = Z_S, KV = Z_F ----
    gemm_p8<<<dim3(2, 200, 1), blk, 0, stream>>>(
        bufZS, MR, 0, c2qb, 768, 0, ca2_qkv_b, bufBig, MR, 0, 0, MR, 256, 256, 256, 0);
    gemm_p8<<<dim3(4, 200, 1), blk, 0, stream>>>(
        bufH, MR, 0, c2qb + 256 * 8, 768, 0, ca2_qkv_b + 256,
        bufBig + (size_t)32 * MR * 8, MR, 0, 0, MR, 512, 512, 256, 0);
    vtrans<<<dim3(7, NHH, NB), blk, 0, stream>>>(bufBig, vT);
    attn_p8<<<dim3(7, NHH, NB), blk, 0, stream>>>(bufBig, vT, bufA);
    gemm_p8<<<dim3(2, 200, 1), blk, 0, stream>>>(
        bufA, MR, 0, c2ob, 256, 0, ca2_out_b, bufB, MR, 0, 0, MR, 256, 256, 256, 0);
    ln_res_p8<<<400, blk, 0, stream>>>(bufZS, bufB, ca2_n_g, ca2_n_b, bufZS);

    // ---- Classifier (MFMA split-K over feature blocks) ----
    cls_gemm<<<400, blk, 0, stream>>>(bufC, bufZS, w1b, partial);
    cls_reduce<<<32, blk, 0, stream>>>(partial, clsh);
    logits_final<<<NB, 128, 0, stream>>>(clsh, cls_b1, cls_w2, cls_b2, (float*)d_out);
}

// Round 7
// 1163.611 us; speedup vs baseline: 1.2609x; 1.1225x over previous
//
#include <hip/hip_runtime.h>
#include <math.h>

// Problem constants
#define NB   64
#define NN   400
#define DD   256
#define NHH  4
#define HDD  64
#define MR   25600            // NB*NN

typedef __attribute__((ext_vector_type(8))) short bf16x8;
typedef __attribute__((ext_vector_type(4))) float f32x4;

__device__ __forceinline__ short f2bf(float x) {
    union { float f; unsigned u; } v; v.f = x;
    return (short)((v.u + 0x7FFFu + ((v.u >> 16) & 1u)) >> 16);
}
__device__ __forceinline__ float bf2f(short s) {
    union { unsigned u; float f; } v; v.u = ((unsigned)(unsigned short)s) << 16;
    return v.f;
}
// async global->LDS, 16 B/lane; src = per-lane addr, LDS dest = wave-uniform base
__device__ __forceinline__ void gl_lds16(const void* g, void* l) {
    __builtin_amdgcn_global_load_lds(
        (const __attribute__((address_space(1))) unsigned*)g,
        (__attribute__((address_space(3))) unsigned*)l, 16, 0, 0);
}

// ---------------------------------------------------------------------------
// P8 layout: element (row, k) lives at ((k>>3)*rows + row)*8 + (k&7) (bf16).
// = the 16x16x32 MFMA fragment layout; staging is contiguous 1 KiB bursts.
// ---------------------------------------------------------------------------

// bf16 GEMM, 128x128 tile, BK=64, single-buffered (dbuf is neutral: barrier
// drains vmcnt anyway — m99/m100), XCD-friendly grid: blockIdx.x = m-tile so
// A-tile re-readers land on the SAME XCD (ids differ by gridDim.x ≡ 0 mod 8).
// Epilogue: LDS bounce -> 16 B coalesced P8 stores.
__global__ __launch_bounds__(256) void gemm_p8(
    const short* __restrict__ A, int arows, long long sA,
    const short* __restrict__ B, int brows, long long sB,
    const float* __restrict__ bias,
    short* __restrict__ C, int crows, int crz, long long sCe,
    int M, int N, int Npad, int K, int relu)
{
    __shared__ short lds[17408];   // staging: A[0..8191] B[8192..16383]; epilogue [128][136]
    short* Al = lds;
    short* Bl = lds + 8192;
    const int tid = threadIdx.x;
    const int z = blockIdx.z;
    const int m0 = blockIdx.x * 128, n0 = blockIdx.y * 128;
    const short* Ab = A + (size_t)z * sA;
    const short* Bb = B + (size_t)z * sB;

    const int w = tid >> 6, lane = tid & 63;
    const int quad = lane >> 4, l15 = lane & 15;
    const int wm = w & 1, wn = w >> 1;

    f32x4 acc[4][4] = {};

    const int KT = K >> 6;
    for (int kt = 0; kt < KT; ++kt) {
        const int gp0 = kt << 3;
#pragma unroll
        for (int pp = 0; pp < 2; ++pp) {
            const int p = w + pp * 4;
            gl_lds16(Ab + ((size_t)(gp0 + p) * arows + m0 + lane) * 8,      &Al[(p * 128) * 8]);
            gl_lds16(Ab + ((size_t)(gp0 + p) * arows + m0 + 64 + lane) * 8, &Al[(p * 128 + 64) * 8]);
            gl_lds16(Bb + ((size_t)(gp0 + p) * brows + n0 + lane) * 8,      &Bl[(p * 128) * 8]);
            gl_lds16(Bb + ((size_t)(gp0 + p) * brows + n0 + 64 + lane) * 8, &Bl[(p * 128 + 64) * 8]);
        }
        __syncthreads();
#pragma unroll
        for (int kb = 0; kb < 2; ++kb) {
            bf16x8 af[4], bfr[4];
#pragma unroll
            for (int mi = 0; mi < 4; ++mi)
                af[mi] = *reinterpret_cast<const bf16x8*>(
                    &Al[((kb * 4 + quad) * 128 + wm * 64 + mi * 16 + l15) * 8]);
#pragma unroll
            for (int ni = 0; ni < 4; ++ni)
                bfr[ni] = *reinterpret_cast<const bf16x8*>(
                    &Bl[((kb * 4 + quad) * 128 + wn * 64 + ni * 16 + l15) * 8]);
#pragma unroll
            for (int mi = 0; mi < 4; ++mi)
#pragma unroll
                for (int ni = 0; ni < 4; ++ni)
                    acc[mi][ni] = __builtin_amdgcn_mfma_f32_16x16x32_bf16(af[mi], bfr[ni], acc[mi][ni], 0, 0, 0);
        }
        __syncthreads();
    }

    // ---- epilogue: acc -> bf16 row-major LDS tile [128][136], then fat stores
#pragma unroll
    for (int mi = 0; mi < 4; ++mi) {
#pragma unroll
        for (int r = 0; r < 4; ++r) {
            int row = wm * 64 + mi * 16 + quad * 4 + r;
#pragma unroll
            for (int ni = 0; ni < 4; ++ni) {
                int col = wn * 64 + ni * 16 + l15;
                int gcol = n0 + col;
                float v = 0.0f;
                if (gcol < N) {
                    v = acc[mi][ni][r];
                    if (bias) v += bias[gcol];
                    if (relu) v = fmaxf(v, 0.0f);
                }
                lds[row * 136 + col] = f2bf(v);
            }
        }
    }
    __syncthreads();
    short* Cbz = C + (size_t)z * sCe;
    const long long zr = (long long)z * crz;
#pragma unroll
    for (int t = 0; t < 8; ++t) {
        int c = t * 256 + tid;          // row-fastest -> 1 KiB wave bursts
        int row = c & 127, p16 = c >> 7;
        int grow = m0 + row;
        int gcol0 = n0 + p16 * 8;
        if (grow < M && gcol0 < Npad) {
            bf16x8 v = *reinterpret_cast<const bf16x8*>(&lds[row * 136 + p16 * 8]);
            *reinterpret_cast<bf16x8*>(
                &Cbz[((size_t)(gcol0 >> 3) * crows + zr + grow) * 8]) = v;
        }
    }
}

// ---------------------------------------------------------------------------
// V transpose: per (b,h), vT[(bh*56 + kp)*64 + d]*8 + (key&7) = V[key][d],
// keys >= 400 zeroed.
// ---------------------------------------------------------------------------
__global__ __launch_bounds__(256) void vtrans(
    const short* __restrict__ qkv, short* __restrict__ vT)
{
    __shared__ short tile[64][66];
    const int c = blockIdx.x, h = blockIdx.y, b = blockIdx.z;
    const int tid = threadIdx.x;
    const size_t bh = (size_t)b * NHH + h;
    for (int t = tid; t < 512; t += 256) {
        int pp = t >> 6, l = t & 63;
        int j = c * 64 + l;
        bf16x8 v;
        if (j < NN)
            v = *reinterpret_cast<const bf16x8*>(
                qkv + (((size_t)(64 + 8 * h + pp)) * MR + (size_t)b * NN + j) * 8);
        else { for (int e = 0; e < 8; ++e) v[e] = 0; }
#pragma unroll
        for (int e = 0; e < 8; ++e) tile[l][pp * 8 + e] = v[e];
    }
    __syncthreads();
    for (int t = tid; t < 512; t += 256) {
        int kq = t >> 6, d = t & 63;
        int kp = c * 8 + kq;
        bf16x8 o;
#pragma unroll
        for (int e = 0; e < 8; ++e) o[e] = tile[kq * 8 + e][d];
        *reinterpret_cast<bf16x8*>(vT + ((bh * 56 + kp) * 64 + d) * 8) = o;
    }
}

// ---------------------------------------------------------------------------
// Attention over P8 QKV buffer (96 planes x MR rows).
// ---------------------------------------------------------------------------
__global__ __launch_bounds__(256) void attn_p8(
    const short* __restrict__ qkv, const short* __restrict__ vT,
    short* __restrict__ Out)
{
    __shared__ short KP[8 * 448 * 8];
    __shared__ short QV[8 * 64 * 8];
    const int qt = blockIdx.x, h = blockIdx.y, b = blockIdx.z;
    const int tid = threadIdx.x;
    const int w = tid >> 6, lane = tid & 63;
    const int quad = lane >> 4, l15 = lane & 15;
    const size_t rowb = (size_t)b * NN;
    const size_t bh = (size_t)b * NHH + h;

    for (int j = w; j < 8; j += 4)
        gl_lds16(qkv + (((size_t)(8 * h + j)) * MR + rowb + qt * 64 + lane) * 8, &QV[(j * 64) * 8]);
    for (int t = w; t < 56; t += 4) {
        int j = t / 7, c = t - j * 7;
        gl_lds16(qkv + (((size_t)(32 + 8 * h + j)) * MR + rowb + c * 64 + lane) * 8,
                 &KP[(j * 448 + c * 64) * 8]);
    }
    __syncthreads();

    bf16x8 aq0 = *reinterpret_cast<const bf16x8*>(&QV[(quad * 64 + w * 16 + l15) * 8]);
    bf16x8 aq1 = *reinterpret_cast<const bf16x8*>(&QV[((4 + quad) * 64 + w * 16 + l15) * 8]);
    f32x4 sacc[25];
#pragma unroll
    for (int nt = 0; nt < 25; ++nt) { sacc[nt][0] = 0; sacc[nt][1] = 0; sacc[nt][2] = 0; sacc[nt][3] = 0; }
#pragma unroll
    for (int nt = 0; nt < 25; ++nt) {
        bf16x8 b0 = *reinterpret_cast<const bf16x8*>(&KP[(quad * 448 + nt * 16 + l15) * 8]);
        bf16x8 b1 = *reinterpret_cast<const bf16x8*>(&KP[((4 + quad) * 448 + nt * 16 + l15) * 8]);
        sacc[nt] = __builtin_amdgcn_mfma_f32_16x16x32_bf16(aq0, b0, sacc[nt], 0, 0, 0);
        sacc[nt] = __builtin_amdgcn_mfma_f32_16x16x32_bf16(aq1, b1, sacc[nt], 0, 0, 0);
    }

    float mx[4] = {-3e38f, -3e38f, -3e38f, -3e38f}, sm[4] = {0, 0, 0, 0};
#pragma unroll
    for (int nt = 0; nt < 25; ++nt)
#pragma unroll
        for (int r = 0; r < 4; ++r) mx[r] = fmaxf(mx[r], sacc[nt][r]);
#pragma unroll
    for (int r = 0; r < 4; ++r) {
        mx[r] = fmaxf(mx[r], __shfl_xor(mx[r], 1));
        mx[r] = fmaxf(mx[r], __shfl_xor(mx[r], 2));
        mx[r] = fmaxf(mx[r], __shfl_xor(mx[r], 4));
        mx[r] = fmaxf(mx[r], __shfl_xor(mx[r], 8));
    }
#pragma unroll
    for (int nt = 0; nt < 25; ++nt)
#pragma unroll
        for (int r = 0; r < 4; ++r) {
            float e = __expf((sacc[nt][r] - mx[r]) * 0.125f);
            sacc[nt][r] = e;
            sm[r] += e;
        }
#pragma unroll
    for (int r = 0; r < 4; ++r) {
        sm[r] += __shfl_xor(sm[r], 1);
        sm[r] += __shfl_xor(sm[r], 2);
        sm[r] += __shfl_xor(sm[r], 4);
        sm[r] += __shfl_xor(sm[r], 8);
    }
    __syncthreads();

#pragma unroll
    for (int nt = 0; nt < 25; ++nt)
#pragma unroll
        for (int r = 0; r < 4; ++r) {
            int colk = nt * 16 + l15;
            KP[((colk >> 3) * 64 + w * 16 + quad * 4 + r) * 8 + (colk & 7)] = f2bf(sacc[nt][r]);
        }
    for (int idx = tid; idx < 1024; idx += 256) KP[25600 + idx] = 0;

    f32x4 oacc[4];
#pragma unroll
    for (int dt = 0; dt < 4; ++dt) { oacc[dt][0] = 0; oacc[dt][1] = 0; oacc[dt][2] = 0; oacc[dt][3] = 0; }
    for (int kt = 0; kt < 13; ++kt) {
        if ((kt & 1) == 0) {
            __syncthreads();
            const int cp = (kt >> 1) * 8;
            gl_lds16(vT + ((bh * 56 + cp + w) * 64 + lane) * 8,     &QV[(w * 64) * 8]);
            gl_lds16(vT + ((bh * 56 + cp + 4 + w) * 64 + lane) * 8, &QV[((4 + w) * 64) * 8]);
            __syncthreads();
        }
        bf16x8 pa = *reinterpret_cast<const bf16x8*>(&KP[((kt * 4 + quad) * 64 + w * 16 + l15) * 8]);
#pragma unroll
        for (int dt = 0; dt < 4; ++dt) {
            bf16x8 vb = *reinterpret_cast<const bf16x8*>(&QV[(((kt & 1) * 4 + quad) * 64 + dt * 16 + l15) * 8]);
            oacc[dt] = __builtin_amdgcn_mfma_f32_16x16x32_bf16(pa, vb, oacc[dt], 0, 0, 0);
        }
    }
#pragma unroll
    for (int r = 0; r < 4; ++r) {
        int row = qt * 64 + w * 16 + quad * 4 + r;
        if (row >= NN) continue;
        float inv = 1.0f / sm[r];
#pragma unroll
        for (int dt = 0; dt < 4; ++dt) {
            int col = dt * 16 + l15;
            Out[(((size_t)(8 * h + (col >> 3))) * MR + rowb + row) * 8 + (col & 7)] =
                f2bf(oacc[dt][r] * inv);
        }
    }
}

// ---------------------------------------------------------------------------
__global__ void conv_p8(const float* __restrict__ src, short* __restrict__ dst,
                        int R, int K, int Kp, int PR)
{
    long long idx = (long long)blockIdx.x * 256 + threadIdx.x;
    if (idx >= (long long)R * Kp) return;
    int r = (int)(idx / Kp), k = (int)(idx - (long long)r * Kp);
    dst[((size_t)(k >> 3) * PR + r) * 8 + (k & 7)] = (k < K) ? f2bf(src[(size_t)r * K + k]) : (short)0;
}

// ---------------------------------------------------------------------------
__global__ __launch_bounds__(256) void w1_p8(
    const float* __restrict__ W1, short* __restrict__ Wp)
{
    __shared__ float tile[128][129];
    const int k0 = blockIdx.x * 128;
    const int tid = threadIdx.x;
    for (int t = 0; t < 16; ++t) {
        int idx = t * 256 + tid;
        int r = idx >> 5, k4 = idx & 31;
        float4 v = *(const float4*)(W1 + (size_t)r * 102400 + k0 + k4 * 4);
        tile[r][k4 * 4 + 0] = v.x; tile[r][k4 * 4 + 1] = v.y;
        tile[r][k4 * 4 + 2] = v.z; tile[r][k4 * 4 + 3] = v.w;
    }
    __syncthreads();
    for (int t = 0; t < 8; ++t) {
        int idx = t * 256 + tid;
        int pidx = idx >> 7, r = idx & 127;
        bf16x8 o;
#pragma unroll
        for (int e = 0; e < 8; ++e) o[e] = f2bf(tile[r][pidx * 8 + e]);
        *reinterpret_cast<bf16x8*>(Wp + (((size_t)(k0 >> 3) + pidx) * 128 + r) * 8) = o;
    }
}

// ---------------------------------------------------------------------------
__global__ void colsum_dinv(const float* __restrict__ sc, float* __restrict__ dinv)
{
    int b = blockIdx.y;
    int j = blockIdx.x * 256 + threadIdx.x;
    if (j >= NN) return;
    const float* p = sc + (size_t)b * NN * NN + j;
    float s = 0.0f;
    for (int i = 0; i < NN; ++i) s += p[(size_t)i * NN];
    dinv[b * NN + j] = (s > 0.0f) ? 1.0f / sqrtf(s) : 0.0f;
}

// ---------------------------------------------------------------------------
__global__ __launch_bounds__(256) void sc_prep(
    const float* __restrict__ sc, const float* __restrict__ dinv,
    short* __restrict__ scb, short* __restrict__ anT)
{
    __shared__ float tile[64][65];
    const int b = blockIdx.z;
    const int i0 = blockIdx.y * 64, j0 = blockIdx.x * 64;
    const int tid = threadIdx.x;
    const float* sb = sc + (size_t)b * NN * NN;
    short* scbb = scb + (size_t)b * 56 * 512 * 8;
    short* anTb = anT + (size_t)b * 56 * 512 * 8;
    for (int e = tid; e < 4096; e += 256) {
        int r = e >> 6, c = e & 63;
        int i = i0 + r, j = j0 + c;
        tile[r][c] = (i < NN && j < NN) ? sb[(size_t)i * NN + j] : 0.0f;
    }
    __syncthreads();
    for (int e = tid; e < 4096; e += 256) {
        int r = e >> 6, c = e & 63;
        int i = i0 + r, j = j0 + c;
        scbb[((size_t)(j >> 3) * 512 + i) * 8 + (j & 7)] = f2bf(tile[r][c]);
        float v = 0.0f;
        if (i < NN && j < NN) v = tile[r][c] * dinv[b * NN + i] * dinv[b * NN + j];
        anTb[((size_t)(i >> 3) * 512 + j) * 8 + (i & 7)] = f2bf(v);
    }
}

// ---------------------------------------------------------------------------
__global__ __launch_bounds__(256) void ln_res_p8(
    const short* __restrict__ x, const short* __restrict__ a,
    const float* __restrict__ g, const float* __restrict__ bb,
    short* __restrict__ y)
{
    __shared__ float gs[256], bs[256];
    __shared__ float red[2][4][64];
    const int tid = threadIdx.x;
    gs[tid] = g[tid]; bs[tid] = bb[tid];
    const int rl = tid & 63;
    const int part = tid >> 6;
    const int row = blockIdx.x * 64 + rl;
    float sum = 0.0f, sq = 0.0f;
    float vv[8][8];
#pragma unroll
    for (int i = 0; i < 8; ++i) {
        int p = part * 8 + i;
        bf16x8 xv = *reinterpret_cast<const bf16x8*>(x + ((size_t)p * MR + row) * 8);
        bf16x8 av = *reinterpret_cast<const bf16x8*>(a + ((size_t)p * MR + row) * 8);
#pragma unroll
        for (int e = 0; e < 8; ++e) {
            float v = bf2f(xv[e]) + bf2f(av[e]);
            vv[i][e] = v;
            sum += v; sq += v * v;
        }
    }
    red[0][part][rl] = sum; red[1][part][rl] = sq;
    __syncthreads();
    sum = red[0][0][rl] + red[0][1][rl] + red[0][2][rl] + red[0][3][rl];
    sq  = red[1][0][rl] + red[1][1][rl] + red[1][2][rl] + red[1][3][rl];
    float mu = sum * (1.0f / 256.0f);
    float var = sq * (1.0f / 256.0f) - mu * mu;
    float rstd = 1.0f / sqrtf(fmaxf(var, 0.0f) + 1e-5f);
#pragma unroll
    for (int i = 0; i < 8; ++i) {
        int p = part * 8 + i;
        bf16x8 o;
#pragma unroll
        for (int e = 0; e < 8; ++e)
            o[e] = f2bf((vv[i][e] - mu) * rstd * gs[p * 8 + e] + bs[p * 8 + e]);
        *reinterpret_cast<bf16x8*>(y + ((size_t)p * MR + row) * 8) = o;
    }
}

// ---------------------------------------------------------------------------
__global__ __launch_bounds__(256) void cls_gemm(
    const short* __restrict__ C1, const short* __restrict__ C2,
    const short* __restrict__ Wp, float* __restrict__ partial)
{
    __shared__ short Al[32 * 64 * 8];
    __shared__ short Wl[8 * 128 * 8];
    const int j = blockIdx.x;
    const int tid = threadIdx.x;
    const int w = tid >> 6, lane = tid & 63;
    const int quad = lane >> 4, l15 = lane & 15;

    for (int s = 0; s < 8; ++s) {
        int idx = s * 256 + tid;
        int p = idx >> 6, b = idx & 63;
        size_t ad = ((size_t)p * MR + (size_t)b * NN + j) * 8;
        bf16x8 a = *reinterpret_cast<const bf16x8*>(C1 + ad);
        bf16x8 c = *reinterpret_cast<const bf16x8*>(C2 + ad);
        bf16x8 o;
#pragma unroll
        for (int e = 0; e < 8; ++e) o[e] = f2bf(0.5f * (bf2f(a[e]) + bf2f(c[e])));
        *reinterpret_cast<bf16x8*>(&Al[(p * 64 + b) * 8]) = o;
    }

    f32x4 acc[4][2] = {};
    const size_t wp0 = (size_t)j * 32;
    for (int s = 0; s < 4; ++s) {
#pragma unroll
        for (int pp = 0; pp < 2; ++pp) {
            int p = w + pp * 4;
            gl_lds16(Wp + ((wp0 + s * 8 + p) * 128 + lane) * 8,      &Wl[(p * 128) * 8]);
            gl_lds16(Wp + ((wp0 + s * 8 + p) * 128 + 64 + lane) * 8, &Wl[(p * 128 + 64) * 8]);
        }
        __syncthreads();
#pragma unroll
        for (int kb = 0; kb < 2; ++kb) {
            bf16x8 af[4], bfr[2];
#pragma unroll
            for (int mi = 0; mi < 4; ++mi)
                af[mi] = *reinterpret_cast<const bf16x8*>(
                    &Al[((s * 8 + kb * 4 + quad) * 64 + mi * 16 + l15) * 8]);
#pragma unroll
            for (int ni = 0; ni < 2; ++ni)
                bfr[ni] = *reinterpret_cast<const bf16x8*>(
                    &Wl[((kb * 4 + quad) * 128 + w * 32 + ni * 16 + l15) * 8]);
#pragma unroll
            for (int mi = 0; mi < 4; ++mi)
#pragma unroll
                for (int ni = 0; ni < 2; ++ni)
                    acc[mi][ni] = __builtin_amdgcn_mfma_f32_16x16x32_bf16(af[mi], bfr[ni], acc[mi][ni], 0, 0, 0);
        }
        __syncthreads();
    }
    float* pj = partial + (size_t)j * 8192;
#pragma unroll
    for (int mi = 0; mi < 4; ++mi)
#pragma unroll
        for (int r = 0; r < 4; ++r) {
            int row = mi * 16 + quad * 4 + r;
#pragma unroll
            for (int ni = 0; ni < 2; ++ni)
                pj[row * 128 + w * 32 + ni * 16 + l15] = acc[mi][ni][r];
        }
}

__global__ void cls_reduce(const float* __restrict__ partial, float* __restrict__ clsh)
{
    int o = blockIdx.x * 256 + threadIdx.x;
    float s = 0.0f;
    for (int kb = 0; kb < 400; ++kb) s += partial[(size_t)kb * 8192 + o];
    clsh[o] = s;
}

__global__ void logits_final(
    const float* __restrict__ clsh, const float* __restrict__ b1,
    const float* __restrict__ w2, const float* __restrict__ b2,
    float* __restrict__ out)
{
    __shared__ float t[128];
    int b = blockIdx.x;
    int tid = threadIdx.x;
    t[tid] = fmaxf(clsh[b * 128 + tid] + b1[tid], 0.0f);
    __syncthreads();
    if (tid < 2) {
        float s = b2[tid];
        for (int o = 0; o < 128; ++o) s += t[o] * w2[tid * 128 + o];
        out[b * 2 + tid] = s;
    }
}

// ---------------------------------------------------------------------------
extern "C" void kernel_launch(void* const* d_in, const int* in_sizes, int n_in,
                              void* d_out, int out_size, void* d_ws, size_t ws_size,
                              hipStream_t stream)
{
    const float* fc        = (const float*)d_in[0];
    const float* sc        = (const float*)d_in[1];
    const float* proj_w    = (const float*)d_in[2];
    const float* proj_b    = (const float*)d_in[3];
    const float* enc_qkv_w = (const float*)d_in[4];
    const float* enc_qkv_b = (const float*)d_in[5];
    const float* enc_out_w = (const float*)d_in[6];
    const float* enc_out_b = (const float*)d_in[7];
    const float* enc_l1_w  = (const float*)d_in[8];
    const float* enc_l1_b  = (const float*)d_in[9];
    const float* enc_l2_w  = (const float*)d_in[10];
    const float* enc_l2_b  = (const float*)d_in[11];
    const float* enc_n1_g  = (const float*)d_in[12];
    const float* enc_n1_b  = (const float*)d_in[13];
    const float* enc_n2_g  = (const float*)d_in[14];
    const float* enc_n2_b  = (const float*)d_in[15];
    const float* gcn_w1    = (const float*)d_in[16];
    const float* gcn_b1    = (const float*)d_in[17];
    const float* gcn_w2    = (const float*)d_in[18];
    const float* gcn_b2    = (const float*)d_in[19];
    const float* ca1_qkv_w = (const float*)d_in[20];
    const float* ca1_qkv_b = (const float*)d_in[21];
    const float* ca1_out_w = (const float*)d_in[22];
    const float* ca1_out_b = (const float*)d_in[23];
    const float* ca1_n_g   = (const float*)d_in[24];
    const float* ca1_n_b   = (const float*)d_in[25];
    const float* ca2_qkv_w = (const float*)d_in[26];
    const float* ca2_qkv_b = (const float*)d_in[27];
    const float* ca2_out_w = (const float*)d_in[28];
    const float* ca2_out_b = (const float*)d_in[29];
    const float* ca2_n_g   = (const float*)d_in[30];
    const float* ca2_n_b   = (const float*)d_in[31];
    const float* cls_w1    = (const float*)d_in[32];
    const float* cls_b1    = (const float*)d_in[33];
    const float* cls_w2    = (const float*)d_in[34];
    const float* cls_b2    = (const float*)d_in[35];

    char* wsb = (char*)d_ws;
    size_t off = 0;
    auto alloc = [&](size_t bytes) { char* r = wsb + off; off += (bytes + 255) & ~(size_t)255; return r; };
    short* bufBig = (short*)alloc((size_t)MR * 1024 * 2);
    short* fcb    = (short*)alloc((size_t)56 * MR * 8 * 2);
    short* anT    = (short*)alloc((size_t)NB * 56 * 512 * 8 * 2);
    short* bufH   = (short*)alloc((size_t)32 * MR * 8 * 2);
    short* bufA   = (short*)alloc((size_t)32 * MR * 8 * 2);
    short* bufB   = (short*)alloc((size_t)32 * MR * 8 * 2);
    short* bufC   = (short*)alloc((size_t)32 * MR * 8 * 2);
    short* bufZS  = (short*)alloc((size_t)32 * MR * 8 * 2);
    short* vT     = (short*)alloc((size_t)NB * NHH * 56 * 64 * 8 * 2);
    short* w1b    = (short*)alloc((size_t)12800 * 128 * 8 * 2);
    short* projwb = (short*)alloc((size_t)56 * 256 * 8 * 2);
    short* qkvwb  = (short*)alloc((size_t)32 * 1536 * 8 * 2);
    short* outwb  = (short*)alloc((size_t)32 * 512 * 8 * 2);
    short* l1wb   = (short*)alloc((size_t)32 * 2048 * 8 * 2);
    short* l2wb   = (short*)alloc((size_t)128 * 512 * 8 * 2);
    short* gw1b   = (short*)alloc((size_t)56 * 256 * 8 * 2);
    short* gw2b   = (short*)alloc((size_t)32 * 256 * 8 * 2);
    short* c1qb   = (short*)alloc((size_t)32 * 768 * 8 * 2);
    short* c1ob   = (short*)alloc((size_t)32 * 256 * 8 * 2);
    short* c2qb   = (short*)alloc((size_t)32 * 768 * 8 * 2);
    short* c2ob   = (short*)alloc((size_t)32 * 256 * 8 * 2);
    float* dinv   = (float*)alloc((size_t)MR * 4);
    float* clsh   = (float*)alloc((size_t)NB * 128 * 4);
    short* scb = bufBig;
    short* XT1 = bufBig + (size_t)64 * 56 * 512 * 8;
    short* h1  = bufBig;
    short* XT2 = XT1;
    float* partial = (float*)fcb;

    dim3 blk(256);
    auto cgrid = [](long long n) { return dim3((unsigned)((n + 255) / 256)); };

    // ---- conversions to P8 ----
    conv_p8<<<cgrid((long long)MR * 448), blk, 0, stream>>>(fc, fcb, MR, 400, 448, MR);
    conv_p8<<<cgrid(256 * 448), blk, 0, stream>>>(proj_w, projwb, 256, 400, 448, 256);
    conv_p8<<<cgrid(1536 * 256), blk, 0, stream>>>(enc_qkv_w, qkvwb, 1536, 256, 256, 1536);
    conv_p8<<<cgrid(512 * 256), blk, 0, stream>>>(enc_out_w, outwb, 512, 256, 256, 512);
    conv_p8<<<cgrid(2048 * 256), blk, 0, stream>>>(enc_l1_w, l1wb, 2048, 256, 256, 2048);
    conv_p8<<<cgrid(512 * 1024), blk, 0, stream>>>(enc_l2_w, l2wb, 512, 1024, 1024, 512);
    conv_p8<<<cgrid(256 * 448), blk, 0, stream>>>(gcn_w1, gw1b, 256, 400, 448, 256);
    conv_p8<<<cgrid(256 * 256), blk, 0, stream>>>(gcn_w2, gw2b, 256, 256, 256, 256);
    conv_p8<<<cgrid(768 * 256), blk, 0, stream>>>(ca1_qkv_w, c1qb, 768, 256, 256, 768);
    conv_p8<<<cgrid(256 * 256), blk, 0, stream>>>(ca1_out_w, c1ob, 256, 256, 256, 256);
    conv_p8<<<cgrid(768 * 256), blk, 0, stream>>>(ca2_qkv_w, c2qb, 768, 256, 256, 768);
    conv_p8<<<cgrid(256 * 256), blk, 0, stream>>>(ca2_out_w, c2ob, 256, 256, 256, 256);
    w1_p8<<<800, blk, 0, stream>>>(cls_w1, w1b);

    // ---- FC branch ----  (grid = (m-tiles, n-tiles) for XCD L2 A-reuse)
    gemm_p8<<<dim3(200, 2, 1), blk, 0, stream>>>(
        fcb, MR, 0, projwb, 256, 0, proj_b, bufH, MR, 0, 0, MR, 256, 256, 448, 0);
    for (int l = 0; l < 2; ++l) {
        gemm_p8<<<dim3(200, 6, 1), blk, 0, stream>>>(
            bufH, MR, 0, qkvwb + (size_t)l * 768 * 8, 1536, 0, enc_qkv_b + l * 768,
            bufBig, MR, 0, 0, MR, 768, 768, 256, 0);
        vtrans<<<dim3(7, NHH, NB), blk, 0, stream>>>(bufBig, vT);
        attn_p8<<<dim3(7, NHH, NB), blk, 0, stream>>>(bufBig, vT, bufA);
        gemm_p8<<<dim3(200, 2, 1), blk, 0, stream>>>(
            bufA, MR, 0, outwb + (size_t)l * 256 * 8, 512, 0, enc_out_b + l * 256,
            bufB, MR, 0, 0, MR, 256, 256, 256, 0);
        ln_res_p8<<<400, blk, 0, stream>>>(bufH, bufB, enc_n1_g + l * DD, enc_n1_b + l * DD, bufH);
        gemm_p8<<<dim3(200, 8, 1), blk, 0, stream>>>(
            bufH, MR, 0, l1wb + (size_t)l * 1024 * 8, 2048, 0, enc_l1_b + l * 1024,
            bufBig, MR, 0, 0, MR, 1024, 1024, 256, 1);
        gemm_p8<<<dim3(200, 2, 1), blk, 0, stream>>>(
            bufBig, MR, 0, l2wb + (size_t)l * 256 * 8, 512, 0, enc_l2_b + l * 256,
            bufA, MR, 0, 0, MR, 256, 256, 1024, 0);
        ln_res_p8<<<400, blk, 0, stream>>>(bufH, bufA, enc_n2_g + l * DD, enc_n2_b + l * DD, bufH);
    }

    // ---- GCN branch ----
    colsum_dinv<<<dim3(2, NB), blk, 0, stream>>>(sc, dinv);
    sc_prep<<<dim3(7, 7, NB), blk, 0, stream>>>(sc, dinv, scb, anT);
    gemm_p8<<<dim3(2, 4, NB), blk, 0, stream>>>(
        gw1b, 256, 0, scb, 512, 56LL * 512 * 8, nullptr,
        XT1, 256, 0, 56LL * 256 * 8, 256, 400, 448, 448, 0);
    gemm_p8<<<dim3(4, 2, NB), blk, 0, stream>>>(
        anT, 512, 56LL * 512 * 8, XT1, 256, 56LL * 256 * 8, gcn_b1,
        h1, 512, 0, 32LL * 512 * 8, 400, 256, 256, 448, 1);
    gemm_p8<<<dim3(2, 4, NB), blk, 0, stream>>>(
        gw2b, 256, 0, h1, 512, 32LL * 512 * 8, nullptr,
        XT2, 256, 0, 56LL * 256 * 8, 256, 400, 448, 256, 0);
    gemm_p8<<<dim3(4, 2, NB), blk, 0, stream>>>(
        anT, 512, 56LL * 512 * 8, XT2, 256, 56LL * 256 * 8, gcn_b2,
        bufZS, MR, 400, 0, 400, 256, 256, 448, 0);

    // ---- Cross attention 1: Q = Z_F, KV = Z_S ----
    gemm_p8<<<dim3(200, 2, 1), blk, 0, stream>>>(
        bufH, MR, 0, c1qb, 768, 0, ca1_qkv_b, bufBig, MR, 0, 0, MR, 256, 256, 256, 0);
    gemm_p8<<<dim3(200, 4, 1), blk, 0, stream>>>(
        bufZS, MR, 0, c1qb + 256 * 8, 768, 0, ca1_qkv_b + 256,
        bufBig + (size_t)32 * MR * 8, MR, 0, 0, MR, 512, 512, 256, 0);
    vtrans<<<dim3(7, NHH, NB), blk, 0, stream>>>(bufBig, vT);
    attn_p8<<<dim3(7, NHH, NB), blk, 0, stream>>>(bufBig, vT, bufA);
    gemm_p8<<<dim3(200, 2, 1), blk, 0, stream>>>(
        bufA, MR, 0, c1ob, 256, 0, ca1_out_b, bufB, MR, 0, 0, MR, 256, 256, 256, 0);
    ln_res_p8<<<400, blk, 0, stream>>>(bufH, bufB, ca1_n_g, ca1_n_b, bufC);

    // ---- Cross attention 2: Q = Z_S, KV = Z_F ----
    gemm_p8<<<dim3(200, 2, 1), blk, 0, stream>>>(
        bufZS, MR, 0, c2qb, 768, 0, ca2_qkv_b, bufBig, MR, 0, 0, MR, 256, 256, 256, 0);
    gemm_p8<<<dim3(200, 4, 1), blk, 0, stream>>>(
        bufH, MR, 0, c2qb + 256 * 8, 768, 0, ca2_qkv_b + 256,
        bufBig + (size_t)32 * MR * 8, MR, 0, 0, MR, 512, 512, 256, 0);
    vtrans<<<dim3(7, NHH, NB), blk, 0, stream>>>(bufBig, vT);
    attn_p8<<<dim3(7, NHH, NB), blk, 0, stream>>>(bufBig, vT, bufA);
    gemm_p8<<<dim3(200, 2, 1), blk, 0, stream>>>(
        bufA, MR, 0, c2ob, 256, 0, ca2_out_b, bufB, MR, 0, 0, MR, 256, 256, 256, 0);
    ln_res_p8<<<400, blk, 0, stream>>>(bufZS, bufB, ca2_n_g, ca2_n_b, bufZS);

    // ---- Classifier ----
    cls_gemm<<<400, blk, 0, stream>>>(bufC, bufZS, w1b, partial);
    cls_reduce<<<32, blk, 0, stream>>>(partial, clsh);
    logits_final<<<NB, 128, 0, stream>>>(clsh, cls_b1, cls_w2, cls_b2, (float*)d_out);
}

// Round 8
// 1105.319 us; speedup vs baseline: 1.3274x; 1.0527x over previous
//
#include <hip/hip_runtime.h>
#include <math.h>

// Problem constants
#define NB   64
#define NN   400
#define DD   256
#define NHH  4
#define HDD  64
#define MR   25600            // NB*NN

typedef __attribute__((ext_vector_type(8))) short bf16x8;
typedef __attribute__((ext_vector_type(4))) float f32x4;

__device__ __forceinline__ short f2bf(float x) {
    union { float f; unsigned u; } v; v.f = x;
    return (short)((v.u + 0x7FFFu + ((v.u >> 16) & 1u)) >> 16);
}
__device__ __forceinline__ float bf2f(short s) {
    union { unsigned u; float f; } v; v.u = ((unsigned)(unsigned short)s) << 16;
    return v.f;
}
// async global->LDS, 16 B/lane; src = per-lane addr, LDS dest = wave-uniform base
__device__ __forceinline__ void gl_lds16(const void* g, void* l) {
    __builtin_amdgcn_global_load_lds(
        (const __attribute__((address_space(1))) unsigned*)g,
        (__attribute__((address_space(3))) unsigned*)l, 16, 0, 0);
}

// ---------------------------------------------------------------------------
// P8 layout: element (row, k) lives at ((k>>3)*rows + row)*8 + (k&7) (bf16).
// = the 16x16x32 MFMA fragment layout; staging is contiguous 1 KiB bursts.
// ---------------------------------------------------------------------------

// bf16 GEMM, 128x128 tile, BK=64, single-buffered, XCD-friendly grid
// (blockIdx.x = m-tile: A re-readers are gridDim.x ≡ 0 mod 8 apart -> same XCD).
__global__ __launch_bounds__(256) void gemm_p8(
    const short* __restrict__ A, int arows, long long sA,
    const short* __restrict__ B, int brows, long long sB,
    const float* __restrict__ bias,
    short* __restrict__ C, int crows, int crz, long long sCe,
    int M, int N, int Npad, int K, int relu)
{
    __shared__ short lds[17408];   // staging A[0..8191] B[8192..16383]; epilogue [128][136]
    short* Al = lds;
    short* Bl = lds + 8192;
    const int tid = threadIdx.x;
    const int z = blockIdx.z;
    const int m0 = blockIdx.x * 128, n0 = blockIdx.y * 128;
    const short* Ab = A + (size_t)z * sA;
    const short* Bb = B + (size_t)z * sB;

    const int w = tid >> 6, lane = tid & 63;
    const int quad = lane >> 4, l15 = lane & 15;
    const int wm = w & 1, wn = w >> 1;

    f32x4 acc[4][4] = {};

    const int KT = K >> 6;
    for (int kt = 0; kt < KT; ++kt) {
        const int gp0 = kt << 3;
#pragma unroll
        for (int pp = 0; pp < 2; ++pp) {
            const int p = w + pp * 4;
            gl_lds16(Ab + ((size_t)(gp0 + p) * arows + m0 + lane) * 8,      &Al[(p * 128) * 8]);
            gl_lds16(Ab + ((size_t)(gp0 + p) * arows + m0 + 64 + lane) * 8, &Al[(p * 128 + 64) * 8]);
            gl_lds16(Bb + ((size_t)(gp0 + p) * brows + n0 + lane) * 8,      &Bl[(p * 128) * 8]);
            gl_lds16(Bb + ((size_t)(gp0 + p) * brows + n0 + 64 + lane) * 8, &Bl[(p * 128 + 64) * 8]);
        }
        __syncthreads();
#pragma unroll
        for (int kb = 0; kb < 2; ++kb) {
            bf16x8 af[4], bfr[4];
#pragma unroll
            for (int mi = 0; mi < 4; ++mi)
                af[mi] = *reinterpret_cast<const bf16x8*>(
                    &Al[((kb * 4 + quad) * 128 + wm * 64 + mi * 16 + l15) * 8]);
#pragma unroll
            for (int ni = 0; ni < 4; ++ni)
                bfr[ni] = *reinterpret_cast<const bf16x8*>(
                    &Bl[((kb * 4 + quad) * 128 + wn * 64 + ni * 16 + l15) * 8]);
#pragma unroll
            for (int mi = 0; mi < 4; ++mi)
#pragma unroll
                for (int ni = 0; ni < 4; ++ni)
                    acc[mi][ni] = __builtin_amdgcn_mfma_f32_16x16x32_bf16(af[mi], bfr[ni], acc[mi][ni], 0, 0, 0);
        }
        __syncthreads();
    }

    // epilogue: acc -> bf16 row-major LDS tile, then 16 B coalesced stores
#pragma unroll
    for (int mi = 0; mi < 4; ++mi) {
#pragma unroll
        for (int r = 0; r < 4; ++r) {
            int row = wm * 64 + mi * 16 + quad * 4 + r;
#pragma unroll
            for (int ni = 0; ni < 4; ++ni) {
                int col = wn * 64 + ni * 16 + l15;
                int gcol = n0 + col;
                float v = 0.0f;
                if (gcol < N) {
                    v = acc[mi][ni][r];
                    if (bias) v += bias[gcol];
                    if (relu) v = fmaxf(v, 0.0f);
                }
                lds[row * 136 + col] = f2bf(v);
            }
        }
    }
    __syncthreads();
    short* Cbz = C + (size_t)z * sCe;
    const long long zr = (long long)z * crz;
#pragma unroll
    for (int t = 0; t < 8; ++t) {
        int c = t * 256 + tid;
        int row = c & 127, p16 = c >> 7;
        int grow = m0 + row;
        int gcol0 = n0 + p16 * 8;
        if (grow < M && gcol0 < Npad) {
            bf16x8 v = *reinterpret_cast<const bf16x8*>(&lds[row * 136 + p16 * 8]);
            *reinterpret_cast<bf16x8*>(
                &Cbz[((size_t)(gcol0 >> 3) * crows + zr + grow) * 8]) = v;
        }
    }
}

// ---------------------------------------------------------------------------
// Fused GEMM (N=256) + residual + LayerNorm. Tile 64m x 256n: one block owns
// complete rows, so LN happens in the epilogue. A/B in P8, out in P8.
// out[row] = LN(resid[row] + bf16(A·B^T + bias)) * g + b.  K % 64 == 0.
// ---------------------------------------------------------------------------
__global__ __launch_bounds__(256) void gemm_ln(
    const short* __restrict__ A,
    const short* __restrict__ B, int brows,
    const float* __restrict__ bias,
    const short* __restrict__ resid,
    const float* __restrict__ g, const float* __restrict__ bb,
    short* __restrict__ out, int K)
{
    __shared__ short lds[20480];        // staging: A [0,4096) 8x64x8 ; B [4096,20480) 8x256x8
    __shared__ float gs[256], bs[256], bi_s[256];
    __shared__ float red[2][4][64];
    short* Al = lds;
    short* Bl = lds + 4096;
    const int tid = threadIdx.x;
    const int m0 = blockIdx.x * 64;
    const int w = tid >> 6, lane = tid & 63;
    const int quad = lane >> 4, l15 = lane & 15;
    gs[tid] = g[tid]; bs[tid] = bb[tid]; bi_s[tid] = bias[tid];

    f32x4 acc[16] = {};
    const int KT = K >> 6;
    for (int kt = 0; kt < KT; ++kt) {
        const int gp0 = kt << 3;
        // A: 8 planes x 64 rows (wave w loads planes w, w+4)
        gl_lds16(A + ((size_t)(gp0 + w) * MR + m0 + lane) * 8,     &Al[(w * 64) * 8]);
        gl_lds16(A + ((size_t)(gp0 + w + 4) * MR + m0 + lane) * 8, &Al[((w + 4) * 64) * 8]);
        // B: 8 planes x 256 cols = 32 chunks, 8 per wave
#pragma unroll
        for (int i = 0; i < 8; ++i) {
            int c = i * 4 + w;
            int p = c >> 2, cq = c & 3;
            gl_lds16(B + ((size_t)(gp0 + p) * brows + cq * 64 + lane) * 8,
                     &Bl[(p * 256 + cq * 64) * 8]);
        }
        __syncthreads();
#pragma unroll
        for (int kb = 0; kb < 2; ++kb) {
            bf16x8 af = *reinterpret_cast<const bf16x8*>(
                &Al[((kb * 4 + quad) * 64 + w * 16 + l15) * 8]);
#pragma unroll
            for (int ni = 0; ni < 16; ++ni) {
                bf16x8 bfr = *reinterpret_cast<const bf16x8*>(
                    &Bl[((kb * 4 + quad) * 256 + ni * 16 + l15) * 8]);
                acc[ni] = __builtin_amdgcn_mfma_f32_16x16x32_bf16(af, bfr, acc[ni], 0, 0, 0);
            }
        }
        __syncthreads();
    }

    // epilogue 1: bias add, round to bf16 (matches old GEMM->global->LN path),
    // into row-tile rowt[64][4 groups][66] (66-stride breaks bank alignment)
    short* rowt = lds;
#pragma unroll
    for (int ni = 0; ni < 16; ++ni) {
        int col = ni * 16 + l15;
        int part = col >> 6, idx = col & 63;
#pragma unroll
        for (int r = 0; r < 4; ++r) {
            int row = w * 16 + quad * 4 + r;
            rowt[row * 264 + part * 66 + idx] = f2bf(acc[ni][r] + bi_s[col]);
        }
    }
    __syncthreads();

    // epilogue 2: thread = (row, quarter): add residual, reduce, normalize
    const int row = tid >> 2, part = tid & 3;
    const int grow = m0 + row;
    float vv[8][8];
    float sum = 0.0f, sq = 0.0f;
#pragma unroll
    for (int i = 0; i < 8; ++i) {
        int plane = part * 8 + i;
        bf16x8 rv = *reinterpret_cast<const bf16x8*>(resid + ((size_t)plane * MR + grow) * 8);
        bf16x8 tv = *reinterpret_cast<const bf16x8*>(&rowt[row * 264 + part * 66 + i * 8]);
#pragma unroll
        for (int e = 0; e < 8; ++e) {
            float v = bf2f(tv[e]) + bf2f(rv[e]);
            vv[i][e] = v; sum += v; sq += v * v;
        }
    }
    red[0][part][row] = sum; red[1][part][row] = sq;
    __syncthreads();
    sum = red[0][0][row] + red[0][1][row] + red[0][2][row] + red[0][3][row];
    sq  = red[1][0][row] + red[1][1][row] + red[1][2][row] + red[1][3][row];
    float mu = sum * (1.0f / 256.0f);
    float var = sq * (1.0f / 256.0f) - mu * mu;
    float rstd = 1.0f / sqrtf(fmaxf(var, 0.0f) + 1e-5f);
#pragma unroll
    for (int i = 0; i < 8; ++i) {
        int plane = part * 8 + i;
        bf16x8 o;
#pragma unroll
        for (int e = 0; e < 8; ++e)
            o[e] = f2bf((vv[i][e] - mu) * rstd * gs[plane * 8 + e] + bs[plane * 8 + e]);
        *reinterpret_cast<bf16x8*>(out + ((size_t)plane * MR + grow) * 8) = o;
    }
}

// ---------------------------------------------------------------------------
// V transpose: per (b,h), vT[(bh*56 + kp)*64 + d]*8 + (key&7) = V[key][d],
// keys >= 400 zeroed.
// ---------------------------------------------------------------------------
__global__ __launch_bounds__(256) void vtrans(
    const short* __restrict__ qkv, short* __restrict__ vT)
{
    __shared__ short tile[64][66];
    const int c = blockIdx.x, h = blockIdx.y, b = blockIdx.z;
    const int tid = threadIdx.x;
    const size_t bh = (size_t)b * NHH + h;
    for (int t = tid; t < 512; t += 256) {
        int pp = t >> 6, l = t & 63;
        int j = c * 64 + l;
        bf16x8 v;
        if (j < NN)
            v = *reinterpret_cast<const bf16x8*>(
                qkv + (((size_t)(64 + 8 * h + pp)) * MR + (size_t)b * NN + j) * 8);
        else { for (int e = 0; e < 8; ++e) v[e] = 0; }
#pragma unroll
        for (int e = 0; e < 8; ++e) tile[l][pp * 8 + e] = v[e];
    }
    __syncthreads();
    for (int t = tid; t < 512; t += 256) {
        int kq = t >> 6, d = t & 63;
        int kp = c * 8 + kq;
        bf16x8 o;
#pragma unroll
        for (int e = 0; e < 8; ++e) o[e] = tile[kq * 8 + e][d];
        *reinterpret_cast<bf16x8*>(vT + ((bh * 56 + kp) * 64 + d) * 8) = o;
    }
}

// ---------------------------------------------------------------------------
// Attention over P8 QKV buffer (96 planes x MR rows).
// ---------------------------------------------------------------------------
__global__ __launch_bounds__(256) void attn_p8(
    const short* __restrict__ qkv, const short* __restrict__ vT,
    short* __restrict__ Out)
{
    __shared__ short KP[8 * 448 * 8];
    __shared__ short QV[8 * 64 * 8];
    const int qt = blockIdx.x, h = blockIdx.y, b = blockIdx.z;
    const int tid = threadIdx.x;
    const int w = tid >> 6, lane = tid & 63;
    const int quad = lane >> 4, l15 = lane & 15;
    const size_t rowb = (size_t)b * NN;
    const size_t bh = (size_t)b * NHH + h;

    for (int j = w; j < 8; j += 4)
        gl_lds16(qkv + (((size_t)(8 * h + j)) * MR + rowb + qt * 64 + lane) * 8, &QV[(j * 64) * 8]);
    for (int t = w; t < 56; t += 4) {
        int j = t / 7, c = t - j * 7;
        gl_lds16(qkv + (((size_t)(32 + 8 * h + j)) * MR + rowb + c * 64 + lane) * 8,
                 &KP[(j * 448 + c * 64) * 8]);
    }
    __syncthreads();

    bf16x8 aq0 = *reinterpret_cast<const bf16x8*>(&QV[(quad * 64 + w * 16 + l15) * 8]);
    bf16x8 aq1 = *reinterpret_cast<const bf16x8*>(&QV[((4 + quad) * 64 + w * 16 + l15) * 8]);
    f32x4 sacc[25];
#pragma unroll
    for (int nt = 0; nt < 25; ++nt) { sacc[nt][0] = 0; sacc[nt][1] = 0; sacc[nt][2] = 0; sacc[nt][3] = 0; }
#pragma unroll
    for (int nt = 0; nt < 25; ++nt) {
        bf16x8 b0 = *reinterpret_cast<const bf16x8*>(&KP[(quad * 448 + nt * 16 + l15) * 8]);
        bf16x8 b1 = *reinterpret_cast<const bf16x8*>(&KP[((4 + quad) * 448 + nt * 16 + l15) * 8]);
        sacc[nt] = __builtin_amdgcn_mfma_f32_16x16x32_bf16(aq0, b0, sacc[nt], 0, 0, 0);
        sacc[nt] = __builtin_amdgcn_mfma_f32_16x16x32_bf16(aq1, b1, sacc[nt], 0, 0, 0);
    }

    float mx[4] = {-3e38f, -3e38f, -3e38f, -3e38f}, sm[4] = {0, 0, 0, 0};
#pragma unroll
    for (int nt = 0; nt < 25; ++nt)
#pragma unroll
        for (int r = 0; r < 4; ++r) mx[r] = fmaxf(mx[r], sacc[nt][r]);
#pragma unroll
    for (int r = 0; r < 4; ++r) {
        mx[r] = fmaxf(mx[r], __shfl_xor(mx[r], 1));
        mx[r] = fmaxf(mx[r], __shfl_xor(mx[r], 2));
        mx[r] = fmaxf(mx[r], __shfl_xor(mx[r], 4));
        mx[r] = fmaxf(mx[r], __shfl_xor(mx[r], 8));
    }
#pragma unroll
    for (int nt = 0; nt < 25; ++nt)
#pragma unroll
        for (int r = 0; r < 4; ++r) {
            float e = __expf((sacc[nt][r] - mx[r]) * 0.125f);
            sacc[nt][r] = e;
            sm[r] += e;
        }
#pragma unroll
    for (int r = 0; r < 4; ++r) {
        sm[r] += __shfl_xor(sm[r], 1);
        sm[r] += __shfl_xor(sm[r], 2);
        sm[r] += __shfl_xor(sm[r], 4);
        sm[r] += __shfl_xor(sm[r], 8);
    }
    __syncthreads();

#pragma unroll
    for (int nt = 0; nt < 25; ++nt)
#pragma unroll
        for (int r = 0; r < 4; ++r) {
            int colk = nt * 16 + l15;
            KP[((colk >> 3) * 64 + w * 16 + quad * 4 + r) * 8 + (colk & 7)] = f2bf(sacc[nt][r]);
        }
    for (int idx = tid; idx < 1024; idx += 256) KP[25600 + idx] = 0;

    f32x4 oacc[4];
#pragma unroll
    for (int dt = 0; dt < 4; ++dt) { oacc[dt][0] = 0; oacc[dt][1] = 0; oacc[dt][2] = 0; oacc[dt][3] = 0; }
    for (int kt = 0; kt < 13; ++kt) {
        if ((kt & 1) == 0) {
            __syncthreads();
            const int cp = (kt >> 1) * 8;
            gl_lds16(vT + ((bh * 56 + cp + w) * 64 + lane) * 8,     &QV[(w * 64) * 8]);
            gl_lds16(vT + ((bh * 56 + cp + 4 + w) * 64 + lane) * 8, &QV[((4 + w) * 64) * 8]);
            __syncthreads();
        }
        bf16x8 pa = *reinterpret_cast<const bf16x8*>(&KP[((kt * 4 + quad) * 64 + w * 16 + l15) * 8]);
#pragma unroll
        for (int dt = 0; dt < 4; ++dt) {
            bf16x8 vb = *reinterpret_cast<const bf16x8*>(&QV[(((kt & 1) * 4 + quad) * 64 + dt * 16 + l15) * 8]);
            oacc[dt] = __builtin_amdgcn_mfma_f32_16x16x32_bf16(pa, vb, oacc[dt], 0, 0, 0);
        }
    }
#pragma unroll
    for (int r = 0; r < 4; ++r) {
        int row = qt * 64 + w * 16 + quad * 4 + r;
        if (row >= NN) continue;
        float inv = 1.0f / sm[r];
#pragma unroll
        for (int dt = 0; dt < 4; ++dt) {
            int col = dt * 16 + l15;
            Out[(((size_t)(8 * h + (col >> 3))) * MR + rowb + row) * 8 + (col & 7)] =
                f2bf(oacc[dt][r] * inv);
        }
    }
}

// ---------------------------------------------------------------------------
__global__ void conv_p8(const float* __restrict__ src, short* __restrict__ dst,
                        int R, int K, int Kp, int PR)
{
    long long idx = (long long)blockIdx.x * 256 + threadIdx.x;
    if (idx >= (long long)R * Kp) return;
    int r = (int)(idx / Kp), k = (int)(idx - (long long)r * Kp);
    dst[((size_t)(k >> 3) * PR + r) * 8 + (k & 7)] = (k < K) ? f2bf(src[(size_t)r * K + k]) : (short)0;
}

// ---------------------------------------------------------------------------
__global__ __launch_bounds__(256) void w1_p8(
    const float* __restrict__ W1, short* __restrict__ Wp)
{
    __shared__ float tile[128][129];
    const int k0 = blockIdx.x * 128;
    const int tid = threadIdx.x;
    for (int t = 0; t < 16; ++t) {
        int idx = t * 256 + tid;
        int r = idx >> 5, k4 = idx & 31;
        float4 v = *(const float4*)(W1 + (size_t)r * 102400 + k0 + k4 * 4);
        tile[r][k4 * 4 + 0] = v.x; tile[r][k4 * 4 + 1] = v.y;
        tile[r][k4 * 4 + 2] = v.z; tile[r][k4 * 4 + 3] = v.w;
    }
    __syncthreads();
    for (int t = 0; t < 8; ++t) {
        int idx = t * 256 + tid;
        int pidx = idx >> 7, r = idx & 127;
        bf16x8 o;
#pragma unroll
        for (int e = 0; e < 8; ++e) o[e] = f2bf(tile[r][pidx * 8 + e]);
        *reinterpret_cast<bf16x8*>(Wp + (((size_t)(k0 >> 3) + pidx) * 128 + r) * 8) = o;
    }
}

// ---------------------------------------------------------------------------
__global__ void colsum_dinv(const float* __restrict__ sc, float* __restrict__ dinv)
{
    int b = blockIdx.y;
    int j = blockIdx.x * 256 + threadIdx.x;
    if (j >= NN) return;
    const float* p = sc + (size_t)b * NN * NN + j;
    float s = 0.0f;
    for (int i = 0; i < NN; ++i) s += p[(size_t)i * NN];
    dinv[b * NN + j] = (s > 0.0f) ? 1.0f / sqrtf(s) : 0.0f;
}

// ---------------------------------------------------------------------------
__global__ __launch_bounds__(256) void sc_prep(
    const float* __restrict__ sc, const float* __restrict__ dinv,
    short* __restrict__ scb, short* __restrict__ anT)
{
    __shared__ float tile[64][65];
    const int b = blockIdx.z;
    const int i0 = blockIdx.y * 64, j0 = blockIdx.x * 64;
    const int tid = threadIdx.x;
    const float* sb = sc + (size_t)b * NN * NN;
    short* scbb = scb + (size_t)b * 56 * 512 * 8;
    short* anTb = anT + (size_t)b * 56 * 512 * 8;
    for (int e = tid; e < 4096; e += 256) {
        int r = e >> 6, c = e & 63;
        int i = i0 + r, j = j0 + c;
        tile[r][c] = (i < NN && j < NN) ? sb[(size_t)i * NN + j] : 0.0f;
    }
    __syncthreads();
    for (int e = tid; e < 4096; e += 256) {
        int r = e >> 6, c = e & 63;
        int i = i0 + r, j = j0 + c;
        scbb[((size_t)(j >> 3) * 512 + i) * 8 + (j & 7)] = f2bf(tile[r][c]);
        float v = 0.0f;
        if (i < NN && j < NN) v = tile[r][c] * dinv[b * NN + i] * dinv[b * NN + j];
        anTb[((size_t)(i >> 3) * 512 + j) * 8 + (i & 7)] = f2bf(v);
    }
}

// ---------------------------------------------------------------------------
__global__ __launch_bounds__(256) void cls_gemm(
    const short* __restrict__ C1, const short* __restrict__ C2,
    const short* __restrict__ Wp, float* __restrict__ partial)
{
    __shared__ short Al[32 * 64 * 8];
    __shared__ short Wl[8 * 128 * 8];
    const int j = blockIdx.x;
    const int tid = threadIdx.x;
    const int w = tid >> 6, lane = tid & 63;
    const int quad = lane >> 4, l15 = lane & 15;

    for (int s = 0; s < 8; ++s) {
        int idx = s * 256 + tid;
        int p = idx >> 6, b = idx & 63;
        size_t ad = ((size_t)p * MR + (size_t)b * NN + j) * 8;
        bf16x8 a = *reinterpret_cast<const bf16x8*>(C1 + ad);
        bf16x8 c = *reinterpret_cast<const bf16x8*>(C2 + ad);
        bf16x8 o;
#pragma unroll
        for (int e = 0; e < 8; ++e) o[e] = f2bf(0.5f * (bf2f(a[e]) + bf2f(c[e])));
        *reinterpret_cast<bf16x8*>(&Al[(p * 64 + b) * 8]) = o;
    }

    f32x4 acc[4][2] = {};
    const size_t wp0 = (size_t)j * 32;
    for (int s = 0; s < 4; ++s) {
#pragma unroll
        for (int pp = 0; pp < 2; ++pp) {
            int p = w + pp * 4;
            gl_lds16(Wp + ((wp0 + s * 8 + p) * 128 + lane) * 8,      &Wl[(p * 128) * 8]);
            gl_lds16(Wp + ((wp0 + s * 8 + p) * 128 + 64 + lane) * 8, &Wl[(p * 128 + 64) * 8]);
        }
        __syncthreads();
#pragma unroll
        for (int kb = 0; kb < 2; ++kb) {
            bf16x8 af[4], bfr[2];
#pragma unroll
            for (int mi = 0; mi < 4; ++mi)
                af[mi] = *reinterpret_cast<const bf16x8*>(
                    &Al[((s * 8 + kb * 4 + quad) * 64 + mi * 16 + l15) * 8]);
#pragma unroll
            for (int ni = 0; ni < 2; ++ni)
                bfr[ni] = *reinterpret_cast<const bf16x8*>(
                    &Wl[((kb * 4 + quad) * 128 + w * 32 + ni * 16 + l15) * 8]);
#pragma unroll
            for (int mi = 0; mi < 4; ++mi)
#pragma unroll
                for (int ni = 0; ni < 2; ++ni)
                    acc[mi][ni] = __builtin_amdgcn_mfma_f32_16x16x32_bf16(af[mi], bfr[ni], acc[mi][ni], 0, 0, 0);
        }
        __syncthreads();
    }
    float* pj = partial + (size_t)j * 8192;
#pragma unroll
    for (int mi = 0; mi < 4; ++mi)
#pragma unroll
        for (int r = 0; r < 4; ++r) {
            int row = mi * 16 + quad * 4 + r;
#pragma unroll
            for (int ni = 0; ni < 2; ++ni)
                pj[row * 128 + w * 32 + ni * 16 + l15] = acc[mi][ni][r];
        }
}

__global__ void cls_reduce(const float* __restrict__ partial, float* __restrict__ clsh)
{
    int o = blockIdx.x * 256 + threadIdx.x;
    float s = 0.0f;
    for (int kb = 0; kb < 400; ++kb) s += partial[(size_t)kb * 8192 + o];
    clsh[o] = s;
}

__global__ void logits_final(
    const float* __restrict__ clsh, const float* __restrict__ b1,
    const float* __restrict__ w2, const float* __restrict__ b2,
    float* __restrict__ out)
{
    __shared__ float t[128];
    int b = blockIdx.x;
    int tid = threadIdx.x;
    t[tid] = fmaxf(clsh[b * 128 + tid] + b1[tid], 0.0f);
    __syncthreads();
    if (tid < 2) {
        float s = b2[tid];
        for (int o = 0; o < 128; ++o) s += t[o] * w2[tid * 128 + o];
        out[b * 2 + tid] = s;
    }
}

// ---------------------------------------------------------------------------
extern "C" void kernel_launch(void* const* d_in, const int* in_sizes, int n_in,
                              void* d_out, int out_size, void* d_ws, size_t ws_size,
                              hipStream_t stream)
{
    const float* fc        = (const float*)d_in[0];
    const float* sc        = (const float*)d_in[1];
    const float* proj_w    = (const float*)d_in[2];
    const float* proj_b    = (const float*)d_in[3];
    const float* enc_qkv_w = (const float*)d_in[4];
    const float* enc_qkv_b = (const float*)d_in[5];
    const float* enc_out_w = (const float*)d_in[6];
    const float* enc_out_b = (const float*)d_in[7];
    const float* enc_l1_w  = (const float*)d_in[8];
    const float* enc_l1_b  = (const float*)d_in[9];
    const float* enc_l2_w  = (const float*)d_in[10];
    const float* enc_l2_b  = (const float*)d_in[11];
    const float* enc_n1_g  = (const float*)d_in[12];
    const float* enc_n1_b  = (const float*)d_in[13];
    const float* enc_n2_g  = (const float*)d_in[14];
    const float* enc_n2_b  = (const float*)d_in[15];
    const float* gcn_w1    = (const float*)d_in[16];
    const float* gcn_b1    = (const float*)d_in[17];
    const float* gcn_w2    = (const float*)d_in[18];
    const float* gcn_b2    = (const float*)d_in[19];
    const float* ca1_qkv_w = (const float*)d_in[20];
    const float* ca1_qkv_b = (const float*)d_in[21];
    const float* ca1_out_w = (const float*)d_in[22];
    const float* ca1_out_b = (const float*)d_in[23];
    const float* ca1_n_g   = (const float*)d_in[24];
    const float* ca1_n_b   = (const float*)d_in[25];
    const float* ca2_qkv_w = (const float*)d_in[26];
    const float* ca2_qkv_b = (const float*)d_in[27];
    const float* ca2_out_w = (const float*)d_in[28];
    const float* ca2_out_b = (const float*)d_in[29];
    const float* ca2_n_g   = (const float*)d_in[30];
    const float* ca2_n_b   = (const float*)d_in[31];
    const float* cls_w1    = (const float*)d_in[32];
    const float* cls_b1    = (const float*)d_in[33];
    const float* cls_w2    = (const float*)d_in[34];
    const float* cls_b2    = (const float*)d_in[35];

    char* wsb = (char*)d_ws;
    size_t off = 0;
    auto alloc = [&](size_t bytes) { char* r = wsb + off; off += (bytes + 255) & ~(size_t)255; return r; };
    short* bufBig = (short*)alloc((size_t)MR * 1024 * 2);
    short* fcb    = (short*)alloc((size_t)56 * MR * 8 * 2);
    short* anT    = (short*)alloc((size_t)NB * 56 * 512 * 8 * 2);
    short* bufH   = (short*)alloc((size_t)32 * MR * 8 * 2);
    short* bufA   = (short*)alloc((size_t)32 * MR * 8 * 2);
    short* bufC   = (short*)alloc((size_t)32 * MR * 8 * 2);
    short* bufZS  = (short*)alloc((size_t)32 * MR * 8 * 2);
    short* vT     = (short*)alloc((size_t)NB * NHH * 56 * 64 * 8 * 2);
    short* w1b    = (short*)alloc((size_t)12800 * 128 * 8 * 2);
    short* projwb = (short*)alloc((size_t)56 * 256 * 8 * 2);
    short* qkvwb  = (short*)alloc((size_t)32 * 1536 * 8 * 2);
    short* outwb  = (short*)alloc((size_t)32 * 512 * 8 * 2);
    short* l1wb   = (short*)alloc((size_t)32 * 2048 * 8 * 2);
    short* l2wb   = (short*)alloc((size_t)128 * 512 * 8 * 2);
    short* gw1b   = (short*)alloc((size_t)56 * 256 * 8 * 2);
    short* gw2b   = (short*)alloc((size_t)32 * 256 * 8 * 2);
    short* c1qb   = (short*)alloc((size_t)32 * 768 * 8 * 2);
    short* c1ob   = (short*)alloc((size_t)32 * 256 * 8 * 2);
    short* c2qb   = (short*)alloc((size_t)32 * 768 * 8 * 2);
    short* c2ob   = (short*)alloc((size_t)32 * 256 * 8 * 2);
    float* dinv   = (float*)alloc((size_t)MR * 4);
    float* clsh   = (float*)alloc((size_t)NB * 128 * 4);
    short* scb = bufBig;
    short* XT1 = bufBig + (size_t)64 * 56 * 512 * 8;
    short* h1  = bufBig;
    short* XT2 = XT1;
    float* partial = (float*)fcb;

    dim3 blk(256);
    auto cgrid = [](long long n) { return dim3((unsigned)((n + 255) / 256)); };

    // ---- conversions to P8 ----
    conv_p8<<<cgrid((long long)MR * 448), blk, 0, stream>>>(fc, fcb, MR, 400, 448, MR);
    conv_p8<<<cgrid(256 * 448), blk, 0, stream>>>(proj_w, projwb, 256, 400, 448, 256);
    conv_p8<<<cgrid(1536 * 256), blk, 0, stream>>>(enc_qkv_w, qkvwb, 1536, 256, 256, 1536);
    conv_p8<<<cgrid(512 * 256), blk, 0, stream>>>(enc_out_w, outwb, 512, 256, 256, 512);
    conv_p8<<<cgrid(2048 * 256), blk, 0, stream>>>(enc_l1_w, l1wb, 2048, 256, 256, 2048);
    conv_p8<<<cgrid(512 * 1024), blk, 0, stream>>>(enc_l2_w, l2wb, 512, 1024, 1024, 512);
    conv_p8<<<cgrid(256 * 448), blk, 0, stream>>>(gcn_w1, gw1b, 256, 400, 448, 256);
    conv_p8<<<cgrid(256 * 256), blk, 0, stream>>>(gcn_w2, gw2b, 256, 256, 256, 256);
    conv_p8<<<cgrid(768 * 256), blk, 0, stream>>>(ca1_qkv_w, c1qb, 768, 256, 256, 768);
    conv_p8<<<cgrid(256 * 256), blk, 0, stream>>>(ca1_out_w, c1ob, 256, 256, 256, 256);
    conv_p8<<<cgrid(768 * 256), blk, 0, stream>>>(ca2_qkv_w, c2qb, 768, 256, 256, 768);
    conv_p8<<<cgrid(256 * 256), blk, 0, stream>>>(ca2_out_w, c2ob, 256, 256, 256, 256);
    w1_p8<<<800, blk, 0, stream>>>(cls_w1, w1b);

    // ---- FC branch ----
    gemm_p8<<<dim3(200, 2, 1), blk, 0, stream>>>(
        fcb, MR, 0, projwb, 256, 0, proj_b, bufH, MR, 0, 0, MR, 256, 256, 448, 0);
    for (int l = 0; l < 2; ++l) {
        gemm_p8<<<dim3(200, 6, 1), blk, 0, stream>>>(
            bufH, MR, 0, qkvwb + (size_t)l * 768 * 8, 1536, 0, enc_qkv_b + l * 768,
            bufBig, MR, 0, 0, MR, 768, 768, 256, 0);
        vtrans<<<dim3(7, NHH, NB), blk, 0, stream>>>(bufBig, vT);
        attn_p8<<<dim3(7, NHH, NB), blk, 0, stream>>>(bufBig, vT, bufA);
        // attn-out GEMM + residual + LN (in-place on bufH)
        gemm_ln<<<400, blk, 0, stream>>>(
            bufA, outwb + (size_t)l * 256 * 8, 512, enc_out_b + l * 256,
            bufH, enc_n1_g + l * DD, enc_n1_b + l * DD, bufH, 256);
        gemm_p8<<<dim3(200, 8, 1), blk, 0, stream>>>(
            bufH, MR, 0, l1wb + (size_t)l * 1024 * 8, 2048, 0, enc_l1_b + l * 1024,
            bufBig, MR, 0, 0, MR, 1024, 1024, 256, 1);
        // FF2 GEMM + residual + LN (in-place on bufH)
        gemm_ln<<<400, blk, 0, stream>>>(
            bufBig, l2wb + (size_t)l * 256 * 8, 512, enc_l2_b + l * 256,
            bufH, enc_n2_g + l * DD, enc_n2_b + l * DD, bufH, 1024);
    }

    // ---- GCN branch ----
    colsum_dinv<<<dim3(2, NB), blk, 0, stream>>>(sc, dinv);
    sc_prep<<<dim3(7, 7, NB), blk, 0, stream>>>(sc, dinv, scb, anT);
    gemm_p8<<<dim3(2, 4, NB), blk, 0, stream>>>(
        gw1b, 256, 0, scb, 512, 56LL * 512 * 8, nullptr,
        XT1, 256, 0, 56LL * 256 * 8, 256, 400, 448, 448, 0);
    gemm_p8<<<dim3(4, 2, NB), blk, 0, stream>>>(
        anT, 512, 56LL * 512 * 8, XT1, 256, 56LL * 256 * 8, gcn_b1,
        h1, 512, 0, 32LL * 512 * 8, 400, 256, 256, 448, 1);
    gemm_p8<<<dim3(2, 4, NB), blk, 0, stream>>>(
        gw2b, 256, 0, h1, 512, 32LL * 512 * 8, nullptr,
        XT2, 256, 0, 56LL * 256 * 8, 256, 400, 448, 256, 0);
    gemm_p8<<<dim3(4, 2, NB), blk, 0, stream>>>(
        anT, 512, 56LL * 512 * 8, XT2, 256, 56LL * 256 * 8, gcn_b2,
        bufZS, MR, 400, 0, 400, 256, 256, 448, 0);

    // ---- Cross attention 1: Q = Z_F, KV = Z_S ----
    gemm_p8<<<dim3(200, 2, 1), blk, 0, stream>>>(
        bufH, MR, 0, c1qb, 768, 0, ca1_qkv_b, bufBig, MR, 0, 0, MR, 256, 256, 256, 0);
    gemm_p8<<<dim3(200, 4, 1), blk, 0, stream>>>(
        bufZS, MR, 0, c1qb + 256 * 8, 768, 0, ca1_qkv_b + 256,
        bufBig + (size_t)32 * MR * 8, MR, 0, 0, MR, 512, 512, 256, 0);
    vtrans<<<dim3(7, NHH, NB), blk, 0, stream>>>(bufBig, vT);
    attn_p8<<<dim3(7, NHH, NB), blk, 0, stream>>>(bufBig, vT, bufA);
    gemm_ln<<<400, blk, 0, stream>>>(
        bufA, c1ob, 256, ca1_out_b, bufH, ca1_n_g, ca1_n_b, bufC, 256);

    // ---- Cross attention 2: Q = Z_S, KV = Z_F ----
    gemm_p8<<<dim3(200, 2, 1), blk, 0, stream>>>(
        bufZS, MR, 0, c2qb, 768, 0, ca2_qkv_b, bufBig, MR, 0, 0, MR, 256, 256, 256, 0);
    gemm_p8<<<dim3(200, 4, 1), blk, 0, stream>>>(
        bufH, MR, 0, c2qb + 256 * 8, 768, 0, ca2_qkv_b + 256,
        bufBig + (size_t)32 * MR * 8, MR, 0, 0, MR, 512, 512, 256, 0);
    vtrans<<<dim3(7, NHH, NB), blk, 0, stream>>>(bufBig, vT);
    attn_p8<<<dim3(7, NHH, NB), blk, 0, stream>>>(bufBig, vT, bufA);
    gemm_ln<<<400, blk, 0, stream>>>(
        bufA, c2ob, 256, ca2_out_b, bufZS, ca2_n_g, ca2_n_b, bufZS, 256);

    // ---- Classifier ----
    cls_gemm<<<400, blk, 0, stream>>>(bufC, bufZS, w1b, partial);
    cls_reduce<<<32, blk, 0, stream>>>(partial, clsh);
    logits_final<<<NB, 128, 0, stream>>>(clsh, cls_b1, cls_w2, cls_b2, (float*)d_out);
}